// Round 2
// baseline (5037.657 us; speedup 1.0000x reference)
//
#include <hip/hip_runtime.h>
#include <cstdint>
#include <cstddef>

// ---------------------------------------------------------------------------
// PointConv Set Abstraction forward, MI355X (gfx950).
// B=8, N=4096, D=61, S=1024, K=32; MLP 64->64->64->128 ; WeightNet 3->8->8->16
// Output: concat( new_xyz [B,3,S], out [B,128,S] ) fp32.
// R1: fix fps_kernel register spill (launch_bounds(256,1), was 60 VGPR + 236MB
//     scratch fetch); tree argmax; single barrier per FPS iter (double-buffered
//     LDS reduction slots). m0/m1/m2 get launch_bounds(256,2) for the same
//     spill reason (in[64]+acc[64] = 128+ VGPRs).
// ---------------------------------------------------------------------------

constexpr int B_ = 8, N_ = 4096, D_ = 61, S_ = 1024, K_ = 32;
constexpr int P_ = B_ * S_ * K_;          // 262144 positions (b,s,k)
constexpr int BS_ = B_ * S_;              // 8192

// ---------------- workspace layout (bytes) ----------------
constexpr size_t OFF_STATS  = 0;          // zeroed each launch (8192 B)
constexpr size_t OFF_FPSIDX = 8192;       // 8192 ints
constexpr size_t OFF_NEWXYZ = 40960;      // [B*S][3] f32
constexpr size_t OFF_KNN    = 139264;     // [P] int
constexpr size_t OFF_PT     = 1187840;    // points transposed [B][N][61] f32
constexpr size_t OFF_Y01    = 9183232;    // [64][P] f32 (y0/y1 in place; later aliased as aggbuf)
constexpr size_t OFF_Y2     = 76292096;   // [128][P] f32
constexpr size_t OFF_W01    = 210509824;  // [8][P] f32
constexpr size_t OFF_W2B    = 218898432;  // [16][P] f32
constexpr size_t OFF_OUTPRE = 235675648;  // [8192][128] f32

// ---------------- host threefry (JAX PRNG reproduction) ----------------
static inline uint32_t rotl32(uint32_t x, int r){ return (x << r) | (x >> (32 - r)); }
static void tf2x32(uint32_t k0, uint32_t k1, uint32_t x0, uint32_t x1,
                   uint32_t* o0, uint32_t* o1){
  uint32_t ks[3] = {k0, k1, k0 ^ k1 ^ 0x1BD11BDAu};
  x0 += ks[0]; x1 += ks[1];
  const int RA[4] = {13,15,26,6}, RB[4] = {17,29,16,24};
  for (int i = 0; i < 5; ++i){
    const int* R = (i & 1) ? RB : RA;
    for (int j = 0; j < 4; ++j){ x0 += x1; x1 = rotl32(x1, R[j]); x1 ^= x0; }
    x0 += ks[(i+1)%3]; x1 += ks[(i+2)%3] + (uint32_t)(i+1);
  }
  *o0 = x0; *o1 = x1;
}
struct StartIdx { int v[8]; };
static StartIdx compute_starts(){
  uint32_t ka, kb;
  tf2x32(0u, 42u, 0u, 1u, &ka, &kb);          // split(key)[1]
  StartIdx s;
  for (int i = 0; i < 8; ++i){
    uint32_t b1, b2;
    tf2x32(ka, kb, 0u, (uint32_t)i, &b1, &b2);
    s.v[i] = (int)((b1 ^ b2) & 4095u);        // MODE 1 (validated in R1)
  }
  return s;
}

// ---------------- transpose points [B,61,N] -> [B,N,61] ----------------
__global__ __launch_bounds__(64) void tr_kernel(const float* __restrict__ pts,
                                                float* __restrict__ pT){
  __shared__ float tile[61][65];
  const int b = blockIdx.x >> 6;
  const int n0 = (blockIdx.x & 63) * 64;
  const int t = threadIdx.x;
  for (int d = 0; d < 61; ++d)
    tile[d][t] = pts[((size_t)b*61 + d)*N_ + n0 + t];
  __syncthreads();
  float* dst = pT + ((size_t)b*N_ + n0 + t)*61;
  for (int d = 0; d < 61; ++d) dst[d] = tile[d][t];
}

// ---------------- FPS: exact reproduction of reference scan ----------------
// 256 threads, 16 pts/thread fully register-resident (launch_bounds(256,1) ->
// 512 VGPR budget). Per iter: distance+min update, adjacent-pair tree argmax
// (first-index tie-break), 64-lane butterfly, lane0 -> LDS slot, ONE barrier,
// every thread scans the 4 slots locally (double-buffered to kill WAR).
__global__ __launch_bounds__(256, 1) void fps_kernel(const float* __restrict__ xyz,
                                                     StartIdx st,
                                                     int* __restrict__ fps_idx,
                                                     float* __restrict__ new_xyz,
                                                     float* __restrict__ out_xyz){
  const int b = blockIdx.x, tid = threadIdx.x;
  const int lane = tid & 63, wv = tid >> 6;
  const float* xb = xyz + (size_t)b*3*N_;
  float px[16], py[16], pz[16], dmin[16];
#pragma unroll
  for (int i = 0; i < 16; ++i){
    int n = tid + 256*i;
    px[i] = xb[n]; py[i] = xb[N_ + n]; pz[i] = xb[2*N_ + n];
    dmin[i] = 1e10f;
  }
  __shared__ float sv[2][4], sx[2][4], sy[2][4], sz[2][4];
  __shared__ int   si[2][4];
  __shared__ float s_cx, s_cy, s_cz;

  int far = st.v[b];
  float cx, cy, cz;
  { // initial centroid broadcast from the owning thread (register-held coords)
    int ot = far & 255, oi = far >> 8;
    if (tid == ot){
      float fx = 0.f, fy = 0.f, fz = 0.f;
#pragma unroll
      for (int i = 0; i < 16; ++i){ if (i == oi){ fx = px[i]; fy = py[i]; fz = pz[i]; } }
      s_cx = fx; s_cy = fy; s_cz = fz;
    }
    __syncthreads();
    cx = s_cx; cy = s_cy; cz = s_cz;
  }

  int parity = 0;
  for (int s = 0; s < S_; ++s){
    if (tid == 0){
      fps_idx[b*S_ + s] = far;
      new_xyz[((size_t)b*S_ + s)*3 + 0] = cx;
      new_xyz[((size_t)b*S_ + s)*3 + 1] = cy;
      new_xyz[((size_t)b*S_ + s)*3 + 2] = cz;
      out_xyz[(size_t)b*3*S_ + s]        = cx;
      out_xyz[(size_t)b*3*S_ + S_ + s]   = cy;
      out_xyz[(size_t)b*3*S_ + 2*S_ + s] = cz;
    }
    // distances + dmin update (exact float semantics as reference: no FMA)
    float dm[16];
#pragma unroll
    for (int i = 0; i < 16; ++i){
      float dx = __fsub_rn(px[i], cx), dy = __fsub_rn(py[i], cy), dz = __fsub_rn(pz[i], cz);
      float d  = __fadd_rn(__fadd_rn(__fmul_rn(dx,dx), __fmul_rn(dy,dy)), __fmul_rn(dz,dz));
      float t  = fminf(dmin[i], d);
      dmin[i] = t; dm[i] = t;
    }
    // adjacent-pair tree argmax over 16 slots (strict >, keep-left on tie ==
    // first/lowest global index, since n = tid + 256*slot is monotone in slot)
    float tv[8], tx[8], ty[8], tz[8]; int ti[8];
#pragma unroll
    for (int i = 0; i < 8; ++i){
      bool t = dm[2*i+1] > dm[2*i];
      tv[i] = t ? dm[2*i+1] : dm[2*i];  ti[i] = t ? (2*i+1) : (2*i);
      tx[i] = t ? px[2*i+1] : px[2*i];  ty[i] = t ? py[2*i+1] : py[2*i];
      tz[i] = t ? pz[2*i+1] : pz[2*i];
    }
#pragma unroll
    for (int i = 0; i < 4; ++i){
      bool t = tv[2*i+1] > tv[2*i];
      tv[i] = t ? tv[2*i+1] : tv[2*i];  ti[i] = t ? ti[2*i+1] : ti[2*i];
      tx[i] = t ? tx[2*i+1] : tx[2*i];  ty[i] = t ? ty[2*i+1] : ty[2*i];
      tz[i] = t ? tz[2*i+1] : tz[2*i];
    }
#pragma unroll
    for (int i = 0; i < 2; ++i){
      bool t = tv[2*i+1] > tv[2*i];
      tv[i] = t ? tv[2*i+1] : tv[2*i];  ti[i] = t ? ti[2*i+1] : ti[2*i];
      tx[i] = t ? tx[2*i+1] : tx[2*i];  ty[i] = t ? ty[2*i+1] : ty[2*i];
      tz[i] = t ? tz[2*i+1] : tz[2*i];
    }
    bool t0 = tv[1] > tv[0];
    float bv = t0 ? tv[1] : tv[0];
    int   bi = tid + 256*(t0 ? ti[1] : ti[0]);
    float bx = t0 ? tx[1] : tx[0], by = t0 ? ty[1] : ty[0], bz = t0 ? tz[1] : tz[0];

    // 64-lane butterfly argmax (global-index tie-break)
#pragma unroll
    for (int off = 32; off >= 1; off >>= 1){
      float ov = __shfl_xor(bv, off), ox = __shfl_xor(bx, off),
            oy = __shfl_xor(by, off), oz = __shfl_xor(bz, off);
      int   oi = __shfl_xor(bi, off);
      bool take = (ov > bv) || (ov == bv && oi < bi);
      if (take){ bv = ov; bi = oi; bx = ox; by = oy; bz = oz; }
    }
    if (lane == 0){
      sv[parity][wv] = bv; si[parity][wv] = bi;
      sx[parity][wv] = bx; sy[parity][wv] = by; sz[parity][wv] = bz;
    }
    __syncthreads();
    // every thread scans the 4 wave winners (identical result everywhere)
    float v = sv[parity][0], xx = sx[parity][0], yy = sy[parity][0], zz = sz[parity][0];
    int ii = si[parity][0];
#pragma unroll
    for (int w = 1; w < 4; ++w){
      float wvv = sv[parity][w]; int wii = si[parity][w];
      bool take = (wvv > v) || (wvv == v && wii < ii);
      if (take){ v = wvv; ii = wii; xx = sx[parity][w]; yy = sy[parity][w]; zz = sz[parity][w]; }
    }
    far = ii; cx = xx; cy = yy; cz = zz;
    parity ^= 1;
  }
}

// ---------------- KNN: 32 smallest sqdist per query, wave per query --------
__global__ __launch_bounds__(256) void knn_kernel(const float* __restrict__ xyz,
                                                  const float* __restrict__ nxyz,
                                                  int* __restrict__ knn_idx){
  __shared__ float dist[4][4096];           // 64 KiB
  const int wv = threadIdx.x >> 6, lane = threadIdx.x & 63;
  const int q = blockIdx.x*4 + wv;          // 0..8191
  const int b = q >> 10;
  const float* xb = xyz + (size_t)b*3*N_;
  const float ax = nxyz[(size_t)q*3], ay = nxyz[(size_t)q*3+1], az = nxyz[(size_t)q*3+2];
  const float sa = __fadd_rn(__fadd_rn(__fmul_rn(ax,ax), __fmul_rn(ay,ay)), __fmul_rn(az,az));
  float* dw = dist[wv];
  float lv = 3.4e38f; int ln = 0;
  for (int i = 0; i < 64; ++i){
    int n = i*64 + lane;
    float x = xb[n], y = xb[N_+n], z = xb[2*N_+n];
    float sb  = __fadd_rn(__fadd_rn(__fmul_rn(x,x), __fmul_rn(y,y)), __fmul_rn(z,z));
    float dot = __fadd_rn(__fadd_rn(__fmul_rn(ax,x), __fmul_rn(ay,y)), __fmul_rn(az,z));
    float d   = __fsub_rn(__fadd_rn(sa, sb), __fmul_rn(2.f, dot));
    dw[n] = d;
    if (d < lv){ lv = d; ln = n; }          // strict <: first index on tie
  }
  __syncthreads();
  int myout = 0;
  for (int r = 0; r < 32; ++r){
    float gv = lv; int gn = ln;
#pragma unroll
    for (int off = 32; off >= 1; off >>= 1){
      float ov = __shfl_xor(gv, off); int on = __shfl_xor(gn, off);
      if (ov < gv || (ov == gv && on < gn)){ gv = ov; gn = on; }
    }
    if (lane == r) myout = gn;
    const int col = gn & 63, row = gn >> 6;
    float v = dw[lane*64 + col];
    if (lane == row){ v = 3.4e38f; dw[lane*64 + col] = 3.4e38f; }
    float nv = v; int nn = lane*64 + col;
#pragma unroll
    for (int off = 32; off >= 1; off >>= 1){
      float ov = __shfl_xor(nv, off); int on = __shfl_xor(nn, off);
      if (ov < nv || (ov == nv && on < nn)){ nv = ov; nn = on; }
    }
    if (lane == col){ lv = nv; ln = nn; }
  }
  if (lane < 32) knn_idx[(size_t)q*32 + lane] = myout;
}

// ---------------- MLP layer 0: gather + 64->64 + bias -> y [64][P] ---------
__global__ __launch_bounds__(256, 2) void m0_kernel(const float* __restrict__ pT,
                                                    const float* __restrict__ xyz,
                                                    const float* __restrict__ nxyz,
                                                    const int* __restrict__ knn_idx,
                                                    const float* __restrict__ w,
                                                    const float* __restrict__ bias,
                                                    float* __restrict__ y){
  __shared__ float Wt[4096]; __shared__ float bb[64];
  for (int t = threadIdx.x; t < 4096; t += 256){ int o = t >> 6, c = t & 63; Wt[c*64+o] = w[o*64+c]; }
  if (threadIdx.x < 64) bb[threadIdx.x] = bias[threadIdx.x];
  __syncthreads();
  const int p = blockIdx.x*256 + threadIdx.x;
  const int b = p >> 15, s = (p & 32767) >> 5;
  const int n = knn_idx[p];
  float in[64];
  {
    const float* xb = xyz + (size_t)b*3*N_;
    const int q = (b << 10) + s;
    in[0] = xb[n]       - nxyz[(size_t)q*3];
    in[1] = xb[N_+n]    - nxyz[(size_t)q*3+1];
    in[2] = xb[2*N_+n]  - nxyz[(size_t)q*3+2];
    const float* pr = pT + ((size_t)b*N_ + n)*61;
#pragma unroll
    for (int d = 0; d < 61; ++d) in[3+d] = pr[d];
  }
  float acc[64];
#pragma unroll
  for (int o = 0; o < 64; ++o) acc[o] = bb[o];
#pragma unroll
  for (int c = 0; c < 64; ++c){
    float x = in[c];
#pragma unroll
    for (int o = 0; o < 64; o += 4){
      float4 w4 = *reinterpret_cast<const float4*>(&Wt[c*64+o]);
      acc[o]   += x*w4.x; acc[o+1] += x*w4.y; acc[o+2] += x*w4.z; acc[o+3] += x*w4.w;
    }
  }
#pragma unroll
  for (int o = 0; o < 64; ++o) y[(size_t)o*P_ + p] = acc[o];
}

// ---------------- generic channel stats: sum & sumsq (double atomics) ------
__global__ __launch_bounds__(256) void stats_kernel(const float* __restrict__ y,
                                                    double* __restrict__ st, int C){
  const int c = blockIdx.x % C, chunk = blockIdx.x / C;   // 8 chunks of 32768
  const float* row = y + (size_t)c*P_ + (size_t)chunk*32768;
  double s = 0.0, q = 0.0;
  for (int i = threadIdx.x; i < 32768; i += 256){ double v = row[i]; s += v; q += v*v; }
  __shared__ double ss[256], qq[256];
  ss[threadIdx.x] = s; qq[threadIdx.x] = q; __syncthreads();
  for (int w = 128; w >= 1; w >>= 1){
    if (threadIdx.x < w){ ss[threadIdx.x] += ss[threadIdx.x+w]; qq[threadIdx.x] += qq[threadIdx.x+w]; }
    __syncthreads();
  }
  if (threadIdx.x == 0){ atomicAdd(&st[c*2], ss[0]); atomicAdd(&st[c*2+1], qq[0]); }
}

// helper: BN scale/shift from stats
__device__ __forceinline__ void bn_coeff(const double* st, const float* g, const float* be,
                                         int c, double cnt, float* sc, float* sh){
  double mean = st[c*2] / cnt;
  double var  = st[c*2+1] / cnt - mean*mean;
  double scale = (double)g[c] / sqrt(var + 1e-5);
  *sc = (float)scale; *sh = (float)((double)be[c] - mean*scale);
}

// ---------------- MLP layer 1: bn(relu) then 64->64, in place --------------
__global__ __launch_bounds__(256, 2) void m1_kernel(float* __restrict__ y,
                                                    const float* __restrict__ w,
                                                    const float* __restrict__ bias,
                                                    const double* __restrict__ st,
                                                    const float* __restrict__ g,
                                                    const float* __restrict__ be){
  __shared__ float Wt[4096]; __shared__ float bb[64], sc[64], sh[64];
  for (int t = threadIdx.x; t < 4096; t += 256){ int o = t >> 6, c = t & 63; Wt[c*64+o] = w[o*64+c]; }
  if (threadIdx.x < 64){
    bn_coeff(st, g, be, threadIdx.x, (double)P_, &sc[threadIdx.x], &sh[threadIdx.x]);
    bb[threadIdx.x] = bias[threadIdx.x];
  }
  __syncthreads();
  const int p = blockIdx.x*256 + threadIdx.x;
  float in[64];
#pragma unroll
  for (int c = 0; c < 64; ++c){
    float x = y[(size_t)c*P_ + p];
    in[c] = fmaxf(0.f, fmaf(x, sc[c], sh[c]));
  }
  float acc[64];
#pragma unroll
  for (int o = 0; o < 64; ++o) acc[o] = bb[o];
#pragma unroll
  for (int c = 0; c < 64; ++c){
    float x = in[c];
#pragma unroll
    for (int o = 0; o < 64; o += 4){
      float4 w4 = *reinterpret_cast<const float4*>(&Wt[c*64+o]);
      acc[o]   += x*w4.x; acc[o+1] += x*w4.y; acc[o+2] += x*w4.z; acc[o+3] += x*w4.w;
    }
  }
#pragma unroll
  for (int o = 0; o < 64; ++o) y[(size_t)o*P_ + p] = acc[o];
}

// ---------------- MLP layer 2: bn(relu) then 64->128 (half per blockIdx.y) -
__global__ __launch_bounds__(256, 2) void m2_kernel(const float* __restrict__ y1,
                                                    float* __restrict__ y2,
                                                    const float* __restrict__ w,
                                                    const float* __restrict__ bias,
                                                    const double* __restrict__ st,
                                                    const float* __restrict__ g,
                                                    const float* __restrict__ be){
  __shared__ float Wt[4096]; __shared__ float bb[64], sc[64], sh[64];
  const int half = blockIdx.y;
  for (int t = threadIdx.x; t < 4096; t += 256){
    int o = t >> 6, c = t & 63;
    Wt[c*64+o] = w[(size_t)(half*64+o)*64 + c];
  }
  if (threadIdx.x < 64){
    bn_coeff(st, g, be, threadIdx.x, (double)P_, &sc[threadIdx.x], &sh[threadIdx.x]);
    bb[threadIdx.x] = bias[half*64 + threadIdx.x];
  }
  __syncthreads();
  const int p = blockIdx.x*256 + threadIdx.x;
  float in[64];
#pragma unroll
  for (int c = 0; c < 64; ++c){
    float x = y1[(size_t)c*P_ + p];
    in[c] = fmaxf(0.f, fmaf(x, sc[c], sh[c]));
  }
  float acc[64];
#pragma unroll
  for (int o = 0; o < 64; ++o) acc[o] = bb[o];
#pragma unroll
  for (int c = 0; c < 64; ++c){
    float x = in[c];
#pragma unroll
    for (int o = 0; o < 64; o += 4){
      float4 w4 = *reinterpret_cast<const float4*>(&Wt[c*64+o]);
      acc[o]   += x*w4.x; acc[o+1] += x*w4.y; acc[o+2] += x*w4.z; acc[o+3] += x*w4.w;
    }
  }
#pragma unroll
  for (int o = 0; o < 64; ++o) y2[(size_t)(half*64+o)*P_ + p] = acc[o];
}

// ---------------- WeightNet layer 0: gather g_norm, 3->8 ------------------
__global__ __launch_bounds__(256) void w0_kernel(const float* __restrict__ xyz,
                                                 const float* __restrict__ nxyz,
                                                 const int* __restrict__ knn_idx,
                                                 const float* __restrict__ w,   // [8][3]
                                                 const float* __restrict__ bias,
                                                 float* __restrict__ wb){
  __shared__ float Wl[24], bb[8];
  if (threadIdx.x < 24) Wl[threadIdx.x] = w[threadIdx.x];
  if (threadIdx.x < 8)  bb[threadIdx.x] = bias[threadIdx.x];
  __syncthreads();
  const int p = blockIdx.x*256 + threadIdx.x;
  const int b = p >> 15, s = (p & 32767) >> 5;
  const int n = knn_idx[p];
  const float* xb = xyz + (size_t)b*3*N_;
  const int q = (b << 10) + s;
  float gx = xb[n]      - nxyz[(size_t)q*3];
  float gy = xb[N_+n]   - nxyz[(size_t)q*3+1];
  float gz = xb[2*N_+n] - nxyz[(size_t)q*3+2];
#pragma unroll
  for (int o = 0; o < 8; ++o){
    float a = bb[o] + gx*Wl[o*3] + gy*Wl[o*3+1] + gz*Wl[o*3+2];
    wb[(size_t)o*P_ + p] = a;
  }
}

// ---------------- WeightNet layer 1: bn relu 8->8 in place ----------------
__global__ __launch_bounds__(256) void w1_kernel(float* __restrict__ wb,
                                                 const float* __restrict__ w,   // [8][8]
                                                 const float* __restrict__ bias,
                                                 const double* __restrict__ st,
                                                 const float* __restrict__ g,
                                                 const float* __restrict__ be){
  __shared__ float Wl[64], bb[8], sc[8], sh[8];
  if (threadIdx.x < 64) Wl[threadIdx.x] = w[threadIdx.x];
  if (threadIdx.x < 8){
    bn_coeff(st, g, be, threadIdx.x, (double)P_, &sc[threadIdx.x], &sh[threadIdx.x]);
    bb[threadIdx.x] = bias[threadIdx.x];
  }
  __syncthreads();
  const int p = blockIdx.x*256 + threadIdx.x;
  float in[8];
#pragma unroll
  for (int c = 0; c < 8; ++c){
    float x = wb[(size_t)c*P_ + p];
    in[c] = fmaxf(0.f, fmaf(x, sc[c], sh[c]));
  }
  float acc[8];
#pragma unroll
  for (int o = 0; o < 8; ++o){
    float a = bb[o];
#pragma unroll
    for (int c = 0; c < 8; ++c) a += in[c]*Wl[o*8+c];
    acc[o] = a;
  }
#pragma unroll
  for (int o = 0; o < 8; ++o) wb[(size_t)o*P_ + p] = acc[o];
}

// ---------------- WeightNet layer 2: bn relu 8->16 ------------------------
__global__ __launch_bounds__(256) void w2_kernel(const float* __restrict__ wb,
                                                 float* __restrict__ wb2,
                                                 const float* __restrict__ w,   // [16][8]
                                                 const float* __restrict__ bias,
                                                 const double* __restrict__ st,
                                                 const float* __restrict__ g,
                                                 const float* __restrict__ be){
  __shared__ float Wl[128], bb[16], sc[8], sh[8];
  if (threadIdx.x < 128) Wl[threadIdx.x] = w[threadIdx.x];
  if (threadIdx.x < 8)
    bn_coeff(st, g, be, threadIdx.x, (double)P_, &sc[threadIdx.x], &sh[threadIdx.x]);
  if (threadIdx.x < 16) bb[threadIdx.x] = bias[threadIdx.x];
  __syncthreads();
  const int p = blockIdx.x*256 + threadIdx.x;
  float in[8];
#pragma unroll
  for (int c = 0; c < 8; ++c){
    float x = wb[(size_t)c*P_ + p];
    in[c] = fmaxf(0.f, fmaf(x, sc[c], sh[c]));
  }
#pragma unroll
  for (int o = 0; o < 16; ++o){
    float a = bb[o];
#pragma unroll
    for (int c = 0; c < 8; ++c) a += in[c]*Wl[o*8+c];
    wb2[(size_t)o*P_ + p] = a;
  }
}

// ---------------- agg: per (b,s) [128,K]x[K,16] -> agg row [2048] ----------
__global__ __launch_bounds__(256) void agg_kernel(const float* __restrict__ y2,
                                                  const float* __restrict__ wb2,
                                                  const double* __restrict__ st2,
                                                  const float* __restrict__ g2,
                                                  const float* __restrict__ be2,
                                                  const double* __restrict__ stw,
                                                  const float* __restrict__ gw,
                                                  const float* __restrict__ bew,
                                                  float* __restrict__ agg){
  __shared__ float f[32*132];      // [k][c] padded
  __shared__ float wt[32*16];      // [k][w]
  __shared__ float sc2[128], sh2[128], scw[16], shw[16];
  const int t = threadIdx.x;
  if (t < 128) bn_coeff(st2, g2, be2, t, (double)P_, &sc2[t], &sh2[t]);
  if (t < 16)  bn_coeff(stw, gw, bew, t, (double)P_, &scw[t], &shw[t]);
  __syncthreads();
  const int bs = blockIdx.x;
  const size_t p0 = (size_t)bs * 32;
  for (int e = t; e < 4096; e += 256){
    int c = e >> 5, k = e & 31;
    float x = y2[(size_t)c*P_ + p0 + k];
    f[k*132 + c] = fmaxf(0.f, fmaf(x, sc2[c], sh2[c]));
  }
  for (int e = t; e < 512; e += 256){
    int w = e >> 5, k = e & 31;
    float x = wb2[(size_t)w*P_ + p0 + k];
    wt[k*16 + w] = fmaxf(0.f, fmaf(x, scw[w], shw[w]));
  }
  __syncthreads();
  const int c = t >> 1, wp = (t & 1) * 8;
  float a0=0,a1=0,a2=0,a3=0,a4=0,a5=0,a6=0,a7=0;
#pragma unroll
  for (int k = 0; k < 32; ++k){
    float fv = f[k*132 + c];
    float4 u = *reinterpret_cast<const float4*>(&wt[k*16 + wp]);
    float4 v = *reinterpret_cast<const float4*>(&wt[k*16 + wp + 4]);
    a0 += fv*u.x; a1 += fv*u.y; a2 += fv*u.z; a3 += fv*u.w;
    a4 += fv*v.x; a5 += fv*v.y; a6 += fv*v.z; a7 += fv*v.w;
  }
  float* dst = agg + (size_t)bs*2048 + c*16 + wp;
  *reinterpret_cast<float4*>(dst)     = make_float4(a0,a1,a2,a3);
  *reinterpret_cast<float4*>(dst + 4) = make_float4(a4,a5,a6,a7);
}

// ---------------- linear GEMM: [8192,2048] x [128,2048]^T + b --------------
__global__ __launch_bounds__(256) void lin_kernel(const float* __restrict__ agg,
                                                  const float* __restrict__ lw,
                                                  const float* __restrict__ lb,
                                                  float* __restrict__ outp){
  __shared__ float A[32*33];        // [r][kk] padded
  __shared__ float Wl[32*128];      // [kk][o]
  __shared__ float lbs[128];
  const int t = threadIdx.x;
  const int r0 = blockIdx.x * 32;
  if (t < 128) lbs[t] = lb[t];
  const int c_lane = t & 31, rg = t >> 5;
  float acc[4][4];
#pragma unroll
  for (int i = 0; i < 4; ++i)
#pragma unroll
    for (int j = 0; j < 4; ++j) acc[i][j] = 0.f;

  for (int kk0 = 0; kk0 < 2048; kk0 += 32){
    __syncthreads();
    {
      int r = t >> 3, kq = (t & 7) * 4;
      float4 v = *reinterpret_cast<const float4*>(&agg[(size_t)(r0 + r)*2048 + kk0 + kq]);
      A[r*33 + kq]   = v.x; A[r*33 + kq+1] = v.y; A[r*33 + kq+2] = v.z; A[r*33 + kq+3] = v.w;
    }
    {
#pragma unroll
      for (int u = 0; u < 4; ++u){
        int fid = t + 256*u;
        int o = fid >> 3, kq = (fid & 7) * 4;
        float4 v = *reinterpret_cast<const float4*>(&lw[(size_t)o*2048 + kk0 + kq]);
        Wl[(kq  )*128 + o] = v.x; Wl[(kq+1)*128 + o] = v.y;
        Wl[(kq+2)*128 + o] = v.z; Wl[(kq+3)*128 + o] = v.w;
      }
    }
    __syncthreads();
#pragma unroll 8
    for (int kk = 0; kk < 32; ++kk){
      float a0 = A[(rg*4+0)*33 + kk], a1 = A[(rg*4+1)*33 + kk],
            a2 = A[(rg*4+2)*33 + kk], a3 = A[(rg*4+3)*33 + kk];
#pragma unroll
      for (int j = 0; j < 4; ++j){
        float wv = Wl[kk*128 + c_lane + 32*j];
        acc[0][j] += a0*wv; acc[1][j] += a1*wv; acc[2][j] += a2*wv; acc[3][j] += a3*wv;
      }
    }
  }
  __syncthreads();
#pragma unroll
  for (int i = 0; i < 4; ++i)
#pragma unroll
    for (int j = 0; j < 4; ++j){
      int o = c_lane + 32*j;
      outp[(size_t)(r0 + rg*4 + i)*128 + o] = acc[i][j] + lbs[o];
    }
}

// ---------------- final BN stats over (b,s) --------------------------------
__global__ __launch_bounds__(128) void statsF_kernel(const float* __restrict__ outp,
                                                     double* __restrict__ st){
  const int c = threadIdx.x;
  const int r0 = blockIdx.x * 128;
  double s = 0.0, q = 0.0;
  for (int r = 0; r < 128; ++r){
    double v = outp[(size_t)(r0 + r)*128 + c];
    s += v; q += v*v;
  }
  atomicAdd(&st[c*2], s); atomicAdd(&st[c*2+1], q);
}

// ---------------- final BN+relu + transpose to [B,128,S] -------------------
__global__ __launch_bounds__(256) void final_kernel(const float* __restrict__ outp,
                                                    const double* __restrict__ st,
                                                    const float* __restrict__ g,
                                                    const float* __restrict__ be,
                                                    float* __restrict__ out){
  const int gid = blockIdx.x*256 + threadIdx.x;     // b*131072 + o*1024 + s
  const int s = gid & 1023, o = (gid >> 10) & 127, b = gid >> 17;
  float sc, sh;
  bn_coeff(st, g, be, o, (double)BS_, &sc, &sh);
  float x = outp[((size_t)(b << 10) + s)*128 + o];
  out[gid] = fmaxf(0.f, fmaf(x, sc, sh));
}

// ---------------------------------------------------------------------------
extern "C" void kernel_launch(void* const* d_in, const int* in_sizes, int n_in,
                              void* d_out, int out_size, void* d_ws, size_t ws_size,
                              hipStream_t stream){
  (void)in_sizes; (void)n_in; (void)out_size; (void)ws_size;
  const float* xyz    = (const float*)d_in[0];
  const float* points = (const float*)d_in[1];
  const float* mw0 = (const float*)d_in[2],  *mb0 = (const float*)d_in[3],
             * mg0 = (const float*)d_in[4],  *me0 = (const float*)d_in[5];
  const float* mw1 = (const float*)d_in[6],  *mb1 = (const float*)d_in[7],
             * mg1 = (const float*)d_in[8],  *me1 = (const float*)d_in[9];
  const float* mw2 = (const float*)d_in[10], *mb2 = (const float*)d_in[11],
             * mg2 = (const float*)d_in[12], *me2 = (const float*)d_in[13];
  const float* ww0 = (const float*)d_in[14], *wb0 = (const float*)d_in[15],
             * wg0 = (const float*)d_in[16], *we0 = (const float*)d_in[17];
  const float* ww1 = (const float*)d_in[18], *wb1 = (const float*)d_in[19],
             * wg1 = (const float*)d_in[20], *we1 = (const float*)d_in[21];
  const float* ww2 = (const float*)d_in[22], *wb2_ = (const float*)d_in[23],
             * wg2 = (const float*)d_in[24], *we2 = (const float*)d_in[25];
  const float* lw  = (const float*)d_in[26], *lb  = (const float*)d_in[27];
  const float* fg  = (const float*)d_in[28], *fb  = (const float*)d_in[29];

  char* ws = (char*)d_ws;
  double* ST0 = (double*)(ws + OFF_STATS);
  double* ST1 = (double*)(ws + OFF_STATS + 1024);
  double* ST2 = (double*)(ws + OFF_STATS + 2048);
  double* SW0 = (double*)(ws + OFF_STATS + 4096);
  double* SW1 = (double*)(ws + OFF_STATS + 4224);
  double* SW2 = (double*)(ws + OFF_STATS + 4352);
  double* STF = (double*)(ws + OFF_STATS + 4608);
  int*   fpsidx = (int*)(ws + OFF_FPSIDX);
  float* nxyz   = (float*)(ws + OFF_NEWXYZ);
  int*   knnidx = (int*)(ws + OFF_KNN);
  float* pT     = (float*)(ws + OFF_PT);
  float* y01    = (float*)(ws + OFF_Y01);
  float* y2     = (float*)(ws + OFF_Y2);
  float* w01    = (float*)(ws + OFF_W01);
  float* w2b    = (float*)(ws + OFF_W2B);
  float* aggbuf = (float*)(ws + OFF_Y01);   // alias: y01 dead after m2
  float* outpre = (float*)(ws + OFF_OUTPRE);

  float* out_xyz  = (float*)d_out;                      // [B,3,S]
  float* out_feat = (float*)d_out + (size_t)B_*3*S_;    // [B,128,S]

  hipMemsetAsync(ws + OFF_STATS, 0, 8192, stream);

  tr_kernel<<<dim3(B_*64), dim3(64), 0, stream>>>(points, pT);

  StartIdx st = compute_starts();
  fps_kernel<<<dim3(B_), dim3(256), 0, stream>>>(xyz, st, fpsidx, nxyz, out_xyz);

  knn_kernel<<<dim3(BS_/4), dim3(256), 0, stream>>>(xyz, nxyz, knnidx);

  m0_kernel<<<dim3(P_/256), dim3(256), 0, stream>>>(pT, xyz, nxyz, knnidx, mw0, mb0, y01);
  stats_kernel<<<dim3(64*8), dim3(256), 0, stream>>>(y01, ST0, 64);
  m1_kernel<<<dim3(P_/256), dim3(256), 0, stream>>>(y01, mw1, mb1, ST0, mg0, me0);
  stats_kernel<<<dim3(64*8), dim3(256), 0, stream>>>(y01, ST1, 64);
  m2_kernel<<<dim3(P_/256, 2), dim3(256), 0, stream>>>(y01, y2, mw2, mb2, ST1, mg1, me1);
  stats_kernel<<<dim3(128*8), dim3(256), 0, stream>>>(y2, ST2, 128);

  w0_kernel<<<dim3(P_/256), dim3(256), 0, stream>>>(xyz, nxyz, knnidx, ww0, wb0, w01);
  stats_kernel<<<dim3(8*8), dim3(256), 0, stream>>>(w01, SW0, 8);
  w1_kernel<<<dim3(P_/256), dim3(256), 0, stream>>>(w01, ww1, wb1, SW0, wg0, we0);
  stats_kernel<<<dim3(8*8), dim3(256), 0, stream>>>(w01, SW1, 8);
  w2_kernel<<<dim3(P_/256), dim3(256), 0, stream>>>(w01, w2b, ww2, wb2_, SW1, wg1, we1);
  stats_kernel<<<dim3(16*8), dim3(256), 0, stream>>>(w2b, SW2, 16);

  agg_kernel<<<dim3(BS_), dim3(256), 0, stream>>>(y2, w2b, ST2, mg2, me2, SW2, wg2, we2, aggbuf);
  lin_kernel<<<dim3(BS_/32), dim3(256), 0, stream>>>(aggbuf, lw, lb, outpre);
  statsF_kernel<<<dim3(BS_/128), dim3(128), 0, stream>>>(outpre, STF);
  final_kernel<<<dim3((B_*128*S_)/256), dim3(256), 0, stream>>>(outpre, STF, fg, fb, out_feat);
}

// Round 3
// 1689.233 us; speedup vs baseline: 2.9822x; 2.9822x over previous
//
#include <hip/hip_runtime.h>
#include <cstdint>
#include <cstddef>

// ---------------------------------------------------------------------------
// PointConv Set Abstraction forward, MI355X (gfx950).
// B=8, N=4096, D=61, S=1024, K=32; MLP 64->64->64->128 ; WeightNet 3->8->8->16
// Output: concat( new_xyz [B,3,S], out [B,128,S] ) fp32.
// R3: fps rewritten. R2 post-mortem: compiler scratch-allocates per-thread
//     arrays regardless of launch_bounds (VGPR=72 cannot hold 64 floats);
//     kernel was latency-bound on dependent L2 scratch chains (9600 cy/iter).
//     New fps: 512 thr x 8 pts as NAMED scalars (no arrays -> guaranteed
//     VGPR), coords staged once in LDS float4 for centroid broadcast,
//     reduction on packed u64 key (dmin_bits<<32 | ~idx) => 2 shfls/step and
//     exact first-index tie-break, one barrier/iter via parity slots.
// ---------------------------------------------------------------------------

constexpr int B_ = 8, N_ = 4096, D_ = 61, S_ = 1024, K_ = 32;
constexpr int P_ = B_ * S_ * K_;          // 262144 positions (b,s,k)
constexpr int BS_ = B_ * S_;              // 8192

// ---------------- workspace layout (bytes) ----------------
constexpr size_t OFF_STATS  = 0;          // zeroed each launch (8192 B)
constexpr size_t OFF_FPSIDX = 8192;       // (unused, kept for layout stability)
constexpr size_t OFF_NEWXYZ = 40960;      // [B*S][3] f32
constexpr size_t OFF_KNN    = 139264;     // [P] int
constexpr size_t OFF_PT     = 1187840;    // points transposed [B][N][61] f32
constexpr size_t OFF_Y01    = 9183232;    // [64][P] f32 (y0/y1 in place; later aliased as aggbuf)
constexpr size_t OFF_Y2     = 76292096;   // [128][P] f32
constexpr size_t OFF_W01    = 210509824;  // [8][P] f32
constexpr size_t OFF_W2B    = 218898432;  // [16][P] f32
constexpr size_t OFF_OUTPRE = 235675648;  // [8192][128] f32

// ---------------- host threefry (JAX PRNG reproduction) ----------------
static inline uint32_t rotl32(uint32_t x, int r){ return (x << r) | (x >> (32 - r)); }
static void tf2x32(uint32_t k0, uint32_t k1, uint32_t x0, uint32_t x1,
                   uint32_t* o0, uint32_t* o1){
  uint32_t ks[3] = {k0, k1, k0 ^ k1 ^ 0x1BD11BDAu};
  x0 += ks[0]; x1 += ks[1];
  const int RA[4] = {13,15,26,6}, RB[4] = {17,29,16,24};
  for (int i = 0; i < 5; ++i){
    const int* R = (i & 1) ? RB : RA;
    for (int j = 0; j < 4; ++j){ x0 += x1; x1 = rotl32(x1, R[j]); x1 ^= x0; }
    x0 += ks[(i+1)%3]; x1 += ks[(i+2)%3] + (uint32_t)(i+1);
  }
  *o0 = x0; *o1 = x1;
}
struct StartIdx { int v[8]; };
static StartIdx compute_starts(){
  uint32_t ka, kb;
  tf2x32(0u, 42u, 0u, 1u, &ka, &kb);          // split(key)[1]
  StartIdx s;
  for (int i = 0; i < 8; ++i){
    uint32_t b1, b2;
    tf2x32(ka, kb, 0u, (uint32_t)i, &b1, &b2);
    s.v[i] = (int)((b1 ^ b2) & 4095u);        // MODE 1 (validated in R1)
  }
  return s;
}

// ---------------- transpose points [B,61,N] -> [B,N,61] ----------------
__global__ __launch_bounds__(64) void tr_kernel(const float* __restrict__ pts,
                                                float* __restrict__ pT){
  __shared__ float tile[61][65];
  const int b = blockIdx.x >> 6;
  const int n0 = (blockIdx.x & 63) * 64;
  const int t = threadIdx.x;
  for (int d = 0; d < 61; ++d)
    tile[d][t] = pts[((size_t)b*61 + d)*N_ + n0 + t];
  __syncthreads();
  float* dst = pT + ((size_t)b*N_ + n0 + t)*61;
  for (int d = 0; d < 61; ++d) dst[d] = tile[d][t];
}

// ---------------- FPS: exact reproduction of reference scan ----------------
// 512 threads x 8 points. Per-thread state = 32 NAMED floats (no arrays, no
// scratch). Coords also staged once in LDS float4 for winner broadcast.
// Reduction key: u64 (float_bits(dmin)<<32 | ~global_idx) -> argmax with
// first-index tie-break, 2 shfls per butterfly step, 1 barrier/iter.
#define REP8(M) M(0) M(1) M(2) M(3) M(4) M(5) M(6) M(7)

__global__ __launch_bounds__(512, 1) void fps_kernel(const float* __restrict__ xyz,
                                                     StartIdx st,
                                                     float* __restrict__ new_xyz,
                                                     float* __restrict__ out_xyz){
  const int b = blockIdx.x, tid = threadIdx.x;
  const int lane = tid & 63, wv = tid >> 6;       // 8 waves
  const float* xb = xyz + (size_t)b*3*N_;
  __shared__ float4 pts4[N_];                     // 64 KiB, coords (w unused)
  __shared__ unsigned long long slots[2][8];

#define LOADP(i) \
  float px##i = xb[tid + 512*(i)]; \
  float py##i = xb[N_ + tid + 512*(i)]; \
  float pz##i = xb[2*N_ + tid + 512*(i)]; \
  float dm##i = 1e10f; \
  pts4[tid + 512*(i)] = make_float4(px##i, py##i, pz##i, 0.f);
  REP8(LOADP)
#undef LOADP
  __syncthreads();

  const int start = st.v[b];
  float4 c4 = pts4[start];
  float cx = c4.x, cy = c4.y, cz = c4.z;

  int par = 0;
  for (int s = 0; s < S_; ++s){
    if (tid == 0){
      new_xyz[((size_t)b*S_ + s)*3 + 0] = cx;
      new_xyz[((size_t)b*S_ + s)*3 + 1] = cy;
      new_xyz[((size_t)b*S_ + s)*3 + 2] = cz;
      out_xyz[(size_t)b*3*S_ + s]        = cx;
      out_xyz[(size_t)b*3*S_ + S_ + s]   = cy;
      out_xyz[(size_t)b*3*S_ + 2*S_ + s] = cz;
    }
    // distance + dmin update (exact reference float semantics: rn ops, no FMA)
#define UPD(i) \
    unsigned long long key##i; { \
      float dx = __fsub_rn(px##i, cx), dy = __fsub_rn(py##i, cy), dz = __fsub_rn(pz##i, cz); \
      float d  = __fadd_rn(__fadd_rn(__fmul_rn(dx,dx), __fmul_rn(dy,dy)), __fmul_rn(dz,dz)); \
      dm##i = fminf(dm##i, d); \
      key##i = ((unsigned long long)__float_as_uint(dm##i) << 32) \
             | (unsigned int)(~(unsigned int)(tid + 512*(i))); }
    REP8(UPD)
#undef UPD
    // tree max over 8 keys (keys are unique: idx differs)
    unsigned long long t0 = key0 > key1 ? key0 : key1;
    unsigned long long t1 = key2 > key3 ? key2 : key3;
    unsigned long long t2 = key4 > key5 ? key4 : key5;
    unsigned long long t3 = key6 > key7 ? key6 : key7;
    unsigned long long u0 = t0 > t1 ? t0 : t1;
    unsigned long long u1 = t2 > t3 ? t2 : t3;
    unsigned long long k  = u0 > u1 ? u0 : u1;
    // 64-lane butterfly max
#pragma unroll
    for (int off = 32; off >= 1; off >>= 1){
      unsigned long long o = __shfl_xor(k, off);
      if (o > k) k = o;
    }
    if (lane == 0) slots[par][wv] = k;
    __syncthreads();
    unsigned long long bk = slots[par][0];
    { unsigned long long v1 = slots[par][1]; if (v1 > bk) bk = v1;
      unsigned long long v2 = slots[par][2]; if (v2 > bk) bk = v2;
      unsigned long long v3 = slots[par][3]; if (v3 > bk) bk = v3;
      unsigned long long v4 = slots[par][4]; if (v4 > bk) bk = v4;
      unsigned long long v5 = slots[par][5]; if (v5 > bk) bk = v5;
      unsigned long long v6 = slots[par][6]; if (v6 > bk) bk = v6;
      unsigned long long v7 = slots[par][7]; if (v7 > bk) bk = v7; }
    const int winner = (int)(~(unsigned int)bk) & (N_ - 1);
    float4 w4 = pts4[winner];                    // broadcast read (.xyz stable)
    cx = w4.x; cy = w4.y; cz = w4.z;
    par ^= 1;
  }
}
#undef REP8

// ---------------- KNN: 32 smallest sqdist per query, wave per query --------
__global__ __launch_bounds__(256) void knn_kernel(const float* __restrict__ xyz,
                                                  const float* __restrict__ nxyz,
                                                  int* __restrict__ knn_idx){
  __shared__ float dist[4][4096];           // 64 KiB
  const int wv = threadIdx.x >> 6, lane = threadIdx.x & 63;
  const int q = blockIdx.x*4 + wv;          // 0..8191
  const int b = q >> 10;
  const float* xb = xyz + (size_t)b*3*N_;
  const float ax = nxyz[(size_t)q*3], ay = nxyz[(size_t)q*3+1], az = nxyz[(size_t)q*3+2];
  const float sa = __fadd_rn(__fadd_rn(__fmul_rn(ax,ax), __fmul_rn(ay,ay)), __fmul_rn(az,az));
  float* dw = dist[wv];
  float lv = 3.4e38f; int ln = 0;
  for (int i = 0; i < 64; ++i){
    int n = i*64 + lane;
    float x = xb[n], y = xb[N_+n], z = xb[2*N_+n];
    float sb  = __fadd_rn(__fadd_rn(__fmul_rn(x,x), __fmul_rn(y,y)), __fmul_rn(z,z));
    float dot = __fadd_rn(__fadd_rn(__fmul_rn(ax,x), __fmul_rn(ay,y)), __fmul_rn(az,z));
    float d   = __fsub_rn(__fadd_rn(sa, sb), __fmul_rn(2.f, dot));
    dw[n] = d;
    if (d < lv){ lv = d; ln = n; }          // strict <: first index on tie
  }
  __syncthreads();
  int myout = 0;
  for (int r = 0; r < 32; ++r){
    float gv = lv; int gn = ln;
#pragma unroll
    for (int off = 32; off >= 1; off >>= 1){
      float ov = __shfl_xor(gv, off); int on = __shfl_xor(gn, off);
      if (ov < gv || (ov == gv && on < gn)){ gv = ov; gn = on; }
    }
    if (lane == r) myout = gn;
    const int col = gn & 63, row = gn >> 6;
    float v = dw[lane*64 + col];
    if (lane == row){ v = 3.4e38f; dw[lane*64 + col] = 3.4e38f; }
    float nv = v; int nn = lane*64 + col;
#pragma unroll
    for (int off = 32; off >= 1; off >>= 1){
      float ov = __shfl_xor(nv, off); int on = __shfl_xor(nn, off);
      if (ov < nv || (ov == nv && on < nn)){ nv = ov; nn = on; }
    }
    if (lane == col){ lv = nv; ln = nn; }
  }
  if (lane < 32) knn_idx[(size_t)q*32 + lane] = myout;
}

// ---------------- MLP layer 0: gather + 64->64 + bias -> y [64][P] ---------
__global__ __launch_bounds__(256, 2) void m0_kernel(const float* __restrict__ pT,
                                                    const float* __restrict__ xyz,
                                                    const float* __restrict__ nxyz,
                                                    const int* __restrict__ knn_idx,
                                                    const float* __restrict__ w,
                                                    const float* __restrict__ bias,
                                                    float* __restrict__ y){
  __shared__ float Wt[4096]; __shared__ float bb[64];
  for (int t = threadIdx.x; t < 4096; t += 256){ int o = t >> 6, c = t & 63; Wt[c*64+o] = w[o*64+c]; }
  if (threadIdx.x < 64) bb[threadIdx.x] = bias[threadIdx.x];
  __syncthreads();
  const int p = blockIdx.x*256 + threadIdx.x;
  const int b = p >> 15, s = (p & 32767) >> 5;
  const int n = knn_idx[p];
  float in[64];
  {
    const float* xb = xyz + (size_t)b*3*N_;
    const int q = (b << 10) + s;
    in[0] = xb[n]       - nxyz[(size_t)q*3];
    in[1] = xb[N_+n]    - nxyz[(size_t)q*3+1];
    in[2] = xb[2*N_+n]  - nxyz[(size_t)q*3+2];
    const float* pr = pT + ((size_t)b*N_ + n)*61;
#pragma unroll
    for (int d = 0; d < 61; ++d) in[3+d] = pr[d];
  }
  float acc[64];
#pragma unroll
  for (int o = 0; o < 64; ++o) acc[o] = bb[o];
#pragma unroll
  for (int c = 0; c < 64; ++c){
    float x = in[c];
#pragma unroll
    for (int o = 0; o < 64; o += 4){
      float4 w4 = *reinterpret_cast<const float4*>(&Wt[c*64+o]);
      acc[o]   += x*w4.x; acc[o+1] += x*w4.y; acc[o+2] += x*w4.z; acc[o+3] += x*w4.w;
    }
  }
#pragma unroll
  for (int o = 0; o < 64; ++o) y[(size_t)o*P_ + p] = acc[o];
}

// ---------------- generic channel stats: sum & sumsq (double atomics) ------
__global__ __launch_bounds__(256) void stats_kernel(const float* __restrict__ y,
                                                    double* __restrict__ st, int C){
  const int c = blockIdx.x % C, chunk = blockIdx.x / C;   // 8 chunks of 32768
  const float* row = y + (size_t)c*P_ + (size_t)chunk*32768;
  double s = 0.0, q = 0.0;
  for (int i = threadIdx.x; i < 32768; i += 256){ double v = row[i]; s += v; q += v*v; }
  __shared__ double ss[256], qq[256];
  ss[threadIdx.x] = s; qq[threadIdx.x] = q; __syncthreads();
  for (int w = 128; w >= 1; w >>= 1){
    if (threadIdx.x < w){ ss[threadIdx.x] += ss[threadIdx.x+w]; qq[threadIdx.x] += qq[threadIdx.x+w]; }
    __syncthreads();
  }
  if (threadIdx.x == 0){ atomicAdd(&st[c*2], ss[0]); atomicAdd(&st[c*2+1], qq[0]); }
}

// helper: BN scale/shift from stats
__device__ __forceinline__ void bn_coeff(const double* st, const float* g, const float* be,
                                         int c, double cnt, float* sc, float* sh){
  double mean = st[c*2] / cnt;
  double var  = st[c*2+1] / cnt - mean*mean;
  double scale = (double)g[c] / sqrt(var + 1e-5);
  *sc = (float)scale; *sh = (float)((double)be[c] - mean*scale);
}

// ---------------- MLP layer 1: bn(relu) then 64->64, in place --------------
__global__ __launch_bounds__(256, 2) void m1_kernel(float* __restrict__ y,
                                                    const float* __restrict__ w,
                                                    const float* __restrict__ bias,
                                                    const double* __restrict__ st,
                                                    const float* __restrict__ g,
                                                    const float* __restrict__ be){
  __shared__ float Wt[4096]; __shared__ float bb[64], sc[64], sh[64];
  for (int t = threadIdx.x; t < 4096; t += 256){ int o = t >> 6, c = t & 63; Wt[c*64+o] = w[o*64+c]; }
  if (threadIdx.x < 64){
    bn_coeff(st, g, be, threadIdx.x, (double)P_, &sc[threadIdx.x], &sh[threadIdx.x]);
    bb[threadIdx.x] = bias[threadIdx.x];
  }
  __syncthreads();
  const int p = blockIdx.x*256 + threadIdx.x;
  float in[64];
#pragma unroll
  for (int c = 0; c < 64; ++c){
    float x = y[(size_t)c*P_ + p];
    in[c] = fmaxf(0.f, fmaf(x, sc[c], sh[c]));
  }
  float acc[64];
#pragma unroll
  for (int o = 0; o < 64; ++o) acc[o] = bb[o];
#pragma unroll
  for (int c = 0; c < 64; ++c){
    float x = in[c];
#pragma unroll
    for (int o = 0; o < 64; o += 4){
      float4 w4 = *reinterpret_cast<const float4*>(&Wt[c*64+o]);
      acc[o]   += x*w4.x; acc[o+1] += x*w4.y; acc[o+2] += x*w4.z; acc[o+3] += x*w4.w;
    }
  }
#pragma unroll
  for (int o = 0; o < 64; ++o) y[(size_t)o*P_ + p] = acc[o];
}

// ---------------- MLP layer 2: bn(relu) then 64->128 (half per blockIdx.y) -
__global__ __launch_bounds__(256, 2) void m2_kernel(const float* __restrict__ y1,
                                                    float* __restrict__ y2,
                                                    const float* __restrict__ w,
                                                    const float* __restrict__ bias,
                                                    const double* __restrict__ st,
                                                    const float* __restrict__ g,
                                                    const float* __restrict__ be){
  __shared__ float Wt[4096]; __shared__ float bb[64], sc[64], sh[64];
  const int half = blockIdx.y;
  for (int t = threadIdx.x; t < 4096; t += 256){
    int o = t >> 6, c = t & 63;
    Wt[c*64+o] = w[(size_t)(half*64+o)*64 + c];
  }
  if (threadIdx.x < 64){
    bn_coeff(st, g, be, threadIdx.x, (double)P_, &sc[threadIdx.x], &sh[threadIdx.x]);
    bb[threadIdx.x] = bias[half*64 + threadIdx.x];
  }
  __syncthreads();
  const int p = blockIdx.x*256 + threadIdx.x;
  float in[64];
#pragma unroll
  for (int c = 0; c < 64; ++c){
    float x = y1[(size_t)c*P_ + p];
    in[c] = fmaxf(0.f, fmaf(x, sc[c], sh[c]));
  }
  float acc[64];
#pragma unroll
  for (int o = 0; o < 64; ++o) acc[o] = bb[o];
#pragma unroll
  for (int c = 0; c < 64; ++c){
    float x = in[c];
#pragma unroll
    for (int o = 0; o < 64; o += 4){
      float4 w4 = *reinterpret_cast<const float4*>(&Wt[c*64+o]);
      acc[o]   += x*w4.x; acc[o+1] += x*w4.y; acc[o+2] += x*w4.z; acc[o+3] += x*w4.w;
    }
  }
#pragma unroll
  for (int o = 0; o < 64; ++o) y2[(size_t)(half*64+o)*P_ + p] = acc[o];
}

// ---------------- WeightNet layer 0: gather g_norm, 3->8 ------------------
__global__ __launch_bounds__(256) void w0_kernel(const float* __restrict__ xyz,
                                                 const float* __restrict__ nxyz,
                                                 const int* __restrict__ knn_idx,
                                                 const float* __restrict__ w,   // [8][3]
                                                 const float* __restrict__ bias,
                                                 float* __restrict__ wb){
  __shared__ float Wl[24], bb[8];
  if (threadIdx.x < 24) Wl[threadIdx.x] = w[threadIdx.x];
  if (threadIdx.x < 8)  bb[threadIdx.x] = bias[threadIdx.x];
  __syncthreads();
  const int p = blockIdx.x*256 + threadIdx.x;
  const int b = p >> 15, s = (p & 32767) >> 5;
  const int n = knn_idx[p];
  const float* xb = xyz + (size_t)b*3*N_;
  const int q = (b << 10) + s;
  float gx = xb[n]      - nxyz[(size_t)q*3];
  float gy = xb[N_+n]   - nxyz[(size_t)q*3+1];
  float gz = xb[2*N_+n] - nxyz[(size_t)q*3+2];
#pragma unroll
  for (int o = 0; o < 8; ++o){
    float a = bb[o] + gx*Wl[o*3] + gy*Wl[o*3+1] + gz*Wl[o*3+2];
    wb[(size_t)o*P_ + p] = a;
  }
}

// ---------------- WeightNet layer 1: bn relu 8->8 in place ----------------
__global__ __launch_bounds__(256) void w1_kernel(float* __restrict__ wb,
                                                 const float* __restrict__ w,   // [8][8]
                                                 const float* __restrict__ bias,
                                                 const double* __restrict__ st,
                                                 const float* __restrict__ g,
                                                 const float* __restrict__ be){
  __shared__ float Wl[64], bb[8], sc[8], sh[8];
  if (threadIdx.x < 64) Wl[threadIdx.x] = w[threadIdx.x];
  if (threadIdx.x < 8){
    bn_coeff(st, g, be, threadIdx.x, (double)P_, &sc[threadIdx.x], &sh[threadIdx.x]);
    bb[threadIdx.x] = bias[threadIdx.x];
  }
  __syncthreads();
  const int p = blockIdx.x*256 + threadIdx.x;
  float in[8];
#pragma unroll
  for (int c = 0; c < 8; ++c){
    float x = wb[(size_t)c*P_ + p];
    in[c] = fmaxf(0.f, fmaf(x, sc[c], sh[c]));
  }
  float acc[8];
#pragma unroll
  for (int o = 0; o < 8; ++o){
    float a = bb[o];
#pragma unroll
    for (int c = 0; c < 8; ++c) a += in[c]*Wl[o*8+c];
    acc[o] = a;
  }
#pragma unroll
  for (int o = 0; o < 8; ++o) wb[(size_t)o*P_ + p] = acc[o];
}

// ---------------- WeightNet layer 2: bn relu 8->16 ------------------------
__global__ __launch_bounds__(256) void w2_kernel(const float* __restrict__ wb,
                                                 float* __restrict__ wb2,
                                                 const float* __restrict__ w,   // [16][8]
                                                 const float* __restrict__ bias,
                                                 const double* __restrict__ st,
                                                 const float* __restrict__ g,
                                                 const float* __restrict__ be){
  __shared__ float Wl[128], bb[16], sc[8], sh[8];
  if (threadIdx.x < 128) Wl[threadIdx.x] = w[threadIdx.x];
  if (threadIdx.x < 8)
    bn_coeff(st, g, be, threadIdx.x, (double)P_, &sc[threadIdx.x], &sh[threadIdx.x]);
  if (threadIdx.x < 16) bb[threadIdx.x] = bias[threadIdx.x];
  __syncthreads();
  const int p = blockIdx.x*256 + threadIdx.x;
  float in[8];
#pragma unroll
  for (int c = 0; c < 8; ++c){
    float x = wb[(size_t)c*P_ + p];
    in[c] = fmaxf(0.f, fmaf(x, sc[c], sh[c]));
  }
#pragma unroll
  for (int o = 0; o < 16; ++o){
    float a = bb[o];
#pragma unroll
    for (int c = 0; c < 8; ++c) a += in[c]*Wl[o*8+c];
    wb2[(size_t)o*P_ + p] = a;
  }
}

// ---------------- agg: per (b,s) [128,K]x[K,16] -> agg row [2048] ----------
__global__ __launch_bounds__(256) void agg_kernel(const float* __restrict__ y2,
                                                  const float* __restrict__ wb2,
                                                  const double* __restrict__ st2,
                                                  const float* __restrict__ g2,
                                                  const float* __restrict__ be2,
                                                  const double* __restrict__ stw,
                                                  const float* __restrict__ gw,
                                                  const float* __restrict__ bew,
                                                  float* __restrict__ agg){
  __shared__ float f[32*132];      // [k][c] padded
  __shared__ float wt[32*16];      // [k][w]
  __shared__ float sc2[128], sh2[128], scw[16], shw[16];
  const int t = threadIdx.x;
  if (t < 128) bn_coeff(st2, g2, be2, t, (double)P_, &sc2[t], &sh2[t]);
  if (t < 16)  bn_coeff(stw, gw, bew, t, (double)P_, &scw[t], &shw[t]);
  __syncthreads();
  const int bs = blockIdx.x;
  const size_t p0 = (size_t)bs * 32;
  for (int e = t; e < 4096; e += 256){
    int c = e >> 5, k = e & 31;
    float x = y2[(size_t)c*P_ + p0 + k];
    f[k*132 + c] = fmaxf(0.f, fmaf(x, sc2[c], sh2[c]));
  }
  for (int e = t; e < 512; e += 256){
    int w = e >> 5, k = e & 31;
    float x = wb2[(size_t)w*P_ + p0 + k];
    wt[k*16 + w] = fmaxf(0.f, fmaf(x, scw[w], shw[w]));
  }
  __syncthreads();
  const int c = t >> 1, wp = (t & 1) * 8;
  float a0=0,a1=0,a2=0,a3=0,a4=0,a5=0,a6=0,a7=0;
#pragma unroll
  for (int k = 0; k < 32; ++k){
    float fv = f[k*132 + c];
    float4 u = *reinterpret_cast<const float4*>(&wt[k*16 + wp]);
    float4 v = *reinterpret_cast<const float4*>(&wt[k*16 + wp + 4]);
    a0 += fv*u.x; a1 += fv*u.y; a2 += fv*u.z; a3 += fv*u.w;
    a4 += fv*v.x; a5 += fv*v.y; a6 += fv*v.z; a7 += fv*v.w;
  }
  float* dst = agg + (size_t)bs*2048 + c*16 + wp;
  *reinterpret_cast<float4*>(dst)     = make_float4(a0,a1,a2,a3);
  *reinterpret_cast<float4*>(dst + 4) = make_float4(a4,a5,a6,a7);
}

// ---------------- linear GEMM: [8192,2048] x [128,2048]^T + b --------------
__global__ __launch_bounds__(256) void lin_kernel(const float* __restrict__ agg,
                                                  const float* __restrict__ lw,
                                                  const float* __restrict__ lb,
                                                  float* __restrict__ outp){
  __shared__ float A[32*33];        // [r][kk] padded
  __shared__ float Wl[32*128];      // [kk][o]
  __shared__ float lbs[128];
  const int t = threadIdx.x;
  const int r0 = blockIdx.x * 32;
  if (t < 128) lbs[t] = lb[t];
  const int c_lane = t & 31, rg = t >> 5;
  float acc[4][4];
#pragma unroll
  for (int i = 0; i < 4; ++i)
#pragma unroll
    for (int j = 0; j < 4; ++j) acc[i][j] = 0.f;

  for (int kk0 = 0; kk0 < 2048; kk0 += 32){
    __syncthreads();
    {
      int r = t >> 3, kq = (t & 7) * 4;
      float4 v = *reinterpret_cast<const float4*>(&agg[(size_t)(r0 + r)*2048 + kk0 + kq]);
      A[r*33 + kq]   = v.x; A[r*33 + kq+1] = v.y; A[r*33 + kq+2] = v.z; A[r*33 + kq+3] = v.w;
    }
    {
#pragma unroll
      for (int u = 0; u < 4; ++u){
        int fid = t + 256*u;
        int o = fid >> 3, kq = (fid & 7) * 4;
        float4 v = *reinterpret_cast<const float4*>(&lw[(size_t)o*2048 + kk0 + kq]);
        Wl[(kq  )*128 + o] = v.x; Wl[(kq+1)*128 + o] = v.y;
        Wl[(kq+2)*128 + o] = v.z; Wl[(kq+3)*128 + o] = v.w;
      }
    }
    __syncthreads();
#pragma unroll 8
    for (int kk = 0; kk < 32; ++kk){
      float a0 = A[(rg*4+0)*33 + kk], a1 = A[(rg*4+1)*33 + kk],
            a2 = A[(rg*4+2)*33 + kk], a3 = A[(rg*4+3)*33 + kk];
#pragma unroll
      for (int j = 0; j < 4; ++j){
        float wv = Wl[kk*128 + c_lane + 32*j];
        acc[0][j] += a0*wv; acc[1][j] += a1*wv; acc[2][j] += a2*wv; acc[3][j] += a3*wv;
      }
    }
  }
  __syncthreads();
#pragma unroll
  for (int i = 0; i < 4; ++i)
#pragma unroll
    for (int j = 0; j < 4; ++j){
      int o = c_lane + 32*j;
      outp[(size_t)(r0 + rg*4 + i)*128 + o] = acc[i][j] + lbs[o];
    }
}

// ---------------- final BN stats over (b,s) --------------------------------
__global__ __launch_bounds__(128) void statsF_kernel(const float* __restrict__ outp,
                                                     double* __restrict__ st){
  const int c = threadIdx.x;
  const int r0 = blockIdx.x * 128;
  double s = 0.0, q = 0.0;
  for (int r = 0; r < 128; ++r){
    double v = outp[(size_t)(r0 + r)*128 + c];
    s += v; q += v*v;
  }
  atomicAdd(&st[c*2], s); atomicAdd(&st[c*2+1], q);
}

// ---------------- final BN+relu + transpose to [B,128,S] -------------------
__global__ __launch_bounds__(256) void final_kernel(const float* __restrict__ outp,
                                                    const double* __restrict__ st,
                                                    const float* __restrict__ g,
                                                    const float* __restrict__ be,
                                                    float* __restrict__ out){
  const int gid = blockIdx.x*256 + threadIdx.x;     // b*131072 + o*1024 + s
  const int s = gid & 1023, o = (gid >> 10) & 127, b = gid >> 17;
  float sc, sh;
  bn_coeff(st, g, be, o, (double)BS_, &sc, &sh);
  float x = outp[((size_t)(b << 10) + s)*128 + o];
  out[gid] = fmaxf(0.f, fmaf(x, sc, sh));
}

// ---------------------------------------------------------------------------
extern "C" void kernel_launch(void* const* d_in, const int* in_sizes, int n_in,
                              void* d_out, int out_size, void* d_ws, size_t ws_size,
                              hipStream_t stream){
  (void)in_sizes; (void)n_in; (void)out_size; (void)ws_size;
  const float* xyz    = (const float*)d_in[0];
  const float* points = (const float*)d_in[1];
  const float* mw0 = (const float*)d_in[2],  *mb0 = (const float*)d_in[3],
             * mg0 = (const float*)d_in[4],  *me0 = (const float*)d_in[5];
  const float* mw1 = (const float*)d_in[6],  *mb1 = (const float*)d_in[7],
             * mg1 = (const float*)d_in[8],  *me1 = (const float*)d_in[9];
  const float* mw2 = (const float*)d_in[10], *mb2 = (const float*)d_in[11],
             * mg2 = (const float*)d_in[12], *me2 = (const float*)d_in[13];
  const float* ww0 = (const float*)d_in[14], *wb0 = (const float*)d_in[15],
             * wg0 = (const float*)d_in[16], *we0 = (const float*)d_in[17];
  const float* ww1 = (const float*)d_in[18], *wb1 = (const float*)d_in[19],
             * wg1 = (const float*)d_in[20], *we1 = (const float*)d_in[21];
  const float* ww2 = (const float*)d_in[22], *wb2_ = (const float*)d_in[23],
             * wg2 = (const float*)d_in[24], *we2 = (const float*)d_in[25];
  const float* lw  = (const float*)d_in[26], *lb  = (const float*)d_in[27];
  const float* fg  = (const float*)d_in[28], *fb  = (const float*)d_in[29];

  char* ws = (char*)d_ws;
  double* ST0 = (double*)(ws + OFF_STATS);
  double* ST1 = (double*)(ws + OFF_STATS + 1024);
  double* ST2 = (double*)(ws + OFF_STATS + 2048);
  double* SW0 = (double*)(ws + OFF_STATS + 4096);
  double* SW1 = (double*)(ws + OFF_STATS + 4224);
  double* SW2 = (double*)(ws + OFF_STATS + 4352);
  double* STF = (double*)(ws + OFF_STATS + 4608);
  float* nxyz   = (float*)(ws + OFF_NEWXYZ);
  int*   knnidx = (int*)(ws + OFF_KNN);
  float* pT     = (float*)(ws + OFF_PT);
  float* y01    = (float*)(ws + OFF_Y01);
  float* y2     = (float*)(ws + OFF_Y2);
  float* w01    = (float*)(ws + OFF_W01);
  float* w2b    = (float*)(ws + OFF_W2B);
  float* aggbuf = (float*)(ws + OFF_Y01);   // alias: y01 dead after m2
  float* outpre = (float*)(ws + OFF_OUTPRE);

  float* out_xyz  = (float*)d_out;                      // [B,3,S]
  float* out_feat = (float*)d_out + (size_t)B_*3*S_;    // [B,128,S]

  hipMemsetAsync(ws + OFF_STATS, 0, 8192, stream);

  tr_kernel<<<dim3(B_*64), dim3(64), 0, stream>>>(points, pT);

  StartIdx st = compute_starts();
  fps_kernel<<<dim3(B_), dim3(512), 0, stream>>>(xyz, st, nxyz, out_xyz);

  knn_kernel<<<dim3(BS_/4), dim3(256), 0, stream>>>(xyz, nxyz, knnidx);

  m0_kernel<<<dim3(P_/256), dim3(256), 0, stream>>>(pT, xyz, nxyz, knnidx, mw0, mb0, y01);
  stats_kernel<<<dim3(64*8), dim3(256), 0, stream>>>(y01, ST0, 64);
  m1_kernel<<<dim3(P_/256), dim3(256), 0, stream>>>(y01, mw1, mb1, ST0, mg0, me0);
  stats_kernel<<<dim3(64*8), dim3(256), 0, stream>>>(y01, ST1, 64);
  m2_kernel<<<dim3(P_/256, 2), dim3(256), 0, stream>>>(y01, y2, mw2, mb2, ST1, mg1, me1);
  stats_kernel<<<dim3(128*8), dim3(256), 0, stream>>>(y2, ST2, 128);

  w0_kernel<<<dim3(P_/256), dim3(256), 0, stream>>>(xyz, nxyz, knnidx, ww0, wb0, w01);
  stats_kernel<<<dim3(8*8), dim3(256), 0, stream>>>(w01, SW0, 8);
  w1_kernel<<<dim3(P_/256), dim3(256), 0, stream>>>(w01, ww1, wb1, SW0, wg0, we0);
  stats_kernel<<<dim3(8*8), dim3(256), 0, stream>>>(w01, SW1, 8);
  w2_kernel<<<dim3(P_/256), dim3(256), 0, stream>>>(w01, w2b, ww2, wb2_, SW1, wg1, we1);
  stats_kernel<<<dim3(16*8), dim3(256), 0, stream>>>(w2b, SW2, 16);

  agg_kernel<<<dim3(BS_), dim3(256), 0, stream>>>(y2, w2b, ST2, mg2, me2, SW2, wg2, we2, aggbuf);
  lin_kernel<<<dim3(BS_/32), dim3(256), 0, stream>>>(aggbuf, lw, lb, outpre);
  statsF_kernel<<<dim3(BS_/128), dim3(128), 0, stream>>>(outpre, STF);
  final_kernel<<<dim3((B_*128*S_)/256), dim3(256), 0, stream>>>(outpre, STF, fg, fb, out_feat);
}

// Round 4
// 1558.444 us; speedup vs baseline: 3.2325x; 1.0839x over previous
//
#include <hip/hip_runtime.h>
#include <cstdint>
#include <cstddef>

// ---------------------------------------------------------------------------
// PointConv Set Abstraction forward, MI355X (gfx950).
// B=8, N=4096, D=61, S=1024, K=32; MLP 64->64->64->128 ; WeightNet 3->8->8->16
// Output: concat( new_xyz [B,3,S], out [B,128,S] ) fp32.
// R4: (a) fps reduction via DPP VALU (row_shr/bcast) instead of ds-based
//     shuffles -- R3 post-mortem: 12 dependent DS ops ~1690cy/iter; DPP is
//     ~5cy/step. Two-phase: f32-max chain, then u32-min-index chain, one
//     parity-slot LDS round (validated R3 scheme). (b) knn: DPP u64-key min
//     reduction + swizzled dist LDS (rescan was a 64-way bank conflict).
//     (c) pT padded to 64 floats/row -> float4 gather in m0; tr coalesced;
//     stats float4 loads. outpre aliased over dead w01 region.
// ---------------------------------------------------------------------------

constexpr int B_ = 8, N_ = 4096, D_ = 61, S_ = 1024, K_ = 32;
constexpr int P_ = B_ * S_ * K_;          // 262144 positions (b,s,k)
constexpr int BS_ = B_ * S_;              // 8192

// ---------------- workspace layout (bytes) ----------------
constexpr size_t OFF_STATS  = 0;                          // 8192 B, zeroed
constexpr size_t OFF_NEWXYZ = 8192;                       // [B*S][3] f32
constexpr size_t OFF_KNN    = 106496;                     // [P] int
constexpr size_t OFF_PT     = 1155072;                    // [B*N][64] f32 padded
constexpr size_t OFF_Y01    = 9543680;                    // [64][P] f32 (also aggbuf alias)
constexpr size_t OFF_Y2     = 76652544;                   // [128][P] f32
constexpr size_t OFF_W01    = 210870272;                  // [8][P] f32 (outpre alias after dead)
constexpr size_t OFF_W2B    = 219258880;                  // [16][P] f32
constexpr size_t OFF_OUTPRE = OFF_W01;                    // [8192][128] f32 (w01 dead by lin)
// max end = 236,036,096 B < R3's proven 239,869,952

// ---------------- host threefry (JAX PRNG reproduction) ----------------
static inline uint32_t rotl32(uint32_t x, int r){ return (x << r) | (x >> (32 - r)); }
static void tf2x32(uint32_t k0, uint32_t k1, uint32_t x0, uint32_t x1,
                   uint32_t* o0, uint32_t* o1){
  uint32_t ks[3] = {k0, k1, k0 ^ k1 ^ 0x1BD11BDAu};
  x0 += ks[0]; x1 += ks[1];
  const int RA[4] = {13,15,26,6}, RB[4] = {17,29,16,24};
  for (int i = 0; i < 5; ++i){
    const int* R = (i & 1) ? RB : RA;
    for (int j = 0; j < 4; ++j){ x0 += x1; x1 = rotl32(x1, R[j]); x1 ^= x0; }
    x0 += ks[(i+1)%3]; x1 += ks[(i+2)%3] + (uint32_t)(i+1);
  }
  *o0 = x0; *o1 = x1;
}
struct StartIdx { int v[8]; };
static StartIdx compute_starts(){
  uint32_t ka, kb;
  tf2x32(0u, 42u, 0u, 1u, &ka, &kb);          // split(key)[1]
  StartIdx s;
  for (int i = 0; i < 8; ++i){
    uint32_t b1, b2;
    tf2x32(ka, kb, 0u, (uint32_t)i, &b1, &b2);
    s.v[i] = (int)((b1 ^ b2) & 4095u);        // MODE 1 (validated in R1)
  }
  return s;
}

// ---------------- DPP reduction helpers (wave64) ----------------
// Sequence row_shr 1,2,4,8 then row_bcast15, row_bcast31: lane63 = full reduce.
template<int C>
__device__ __forceinline__ float dpp_max_f32_step(float x){
  // identity 0 is valid: operands are >= 0
  int t = __builtin_amdgcn_update_dpp(0, (int)__float_as_uint(x), C, 0xf, 0xf, true);
  return fmaxf(x, __uint_as_float((unsigned)t));
}
__device__ __forceinline__ float dpp_wave_max_f32(float x){
  x = dpp_max_f32_step<0x111>(x);
  x = dpp_max_f32_step<0x112>(x);
  x = dpp_max_f32_step<0x114>(x);
  x = dpp_max_f32_step<0x118>(x);
  x = dpp_max_f32_step<0x142>(x);
  x = dpp_max_f32_step<0x143>(x);
  return __uint_as_float((unsigned)__builtin_amdgcn_readlane((int)__float_as_uint(x), 63));
}
template<int C>
__device__ __forceinline__ unsigned dpp_min_u32_step(unsigned x){
  int t = __builtin_amdgcn_update_dpp(-1, (int)x, C, 0xf, 0xf, false); // identity ~0
  unsigned u = (unsigned)t;
  return u < x ? u : x;
}
__device__ __forceinline__ unsigned dpp_wave_min_u32(unsigned x){
  x = dpp_min_u32_step<0x111>(x);
  x = dpp_min_u32_step<0x112>(x);
  x = dpp_min_u32_step<0x114>(x);
  x = dpp_min_u32_step<0x118>(x);
  x = dpp_min_u32_step<0x142>(x);
  x = dpp_min_u32_step<0x143>(x);
  return (unsigned)__builtin_amdgcn_readlane((int)x, 63);
}
template<int C>
__device__ __forceinline__ unsigned long long dpp_min_u64_step(unsigned long long k){
  unsigned lo = (unsigned)k, hi = (unsigned)(k >> 32);
  unsigned olo = (unsigned)__builtin_amdgcn_update_dpp(-1, (int)lo, C, 0xf, 0xf, false);
  unsigned ohi = (unsigned)__builtin_amdgcn_update_dpp(-1, (int)hi, C, 0xf, 0xf, false);
  unsigned long long o = ((unsigned long long)ohi << 32) | olo;
  return o < k ? o : k;
}
__device__ __forceinline__ unsigned long long dpp_wave_min_u64(unsigned long long k){
  k = dpp_min_u64_step<0x111>(k);
  k = dpp_min_u64_step<0x112>(k);
  k = dpp_min_u64_step<0x114>(k);
  k = dpp_min_u64_step<0x118>(k);
  k = dpp_min_u64_step<0x142>(k);
  k = dpp_min_u64_step<0x143>(k);
  unsigned lo = (unsigned)__builtin_amdgcn_readlane((int)(unsigned)k, 63);
  unsigned hi = (unsigned)__builtin_amdgcn_readlane((int)(unsigned)(k >> 32), 63);
  return ((unsigned long long)hi << 32) | lo;
}
// order-preserving float->uint (handles negatives; ascending)
__device__ __forceinline__ unsigned ordf(float f){
  unsigned u = __float_as_uint(f);
  return u ^ (unsigned)(((int)u >> 31) | 0x80000000);
}

// ---------------- transpose points [B,61,N] -> [B][N][64] padded -----------
__global__ __launch_bounds__(64) void tr_kernel(const float* __restrict__ pts,
                                                float* __restrict__ pT){
  __shared__ float tile[61][65];
  const int b = blockIdx.x >> 6;
  const int n0 = (blockIdx.x & 63) * 64;
  const int t = threadIdx.x;
  for (int d = 0; d < 61; ++d)
    tile[d][t] = pts[((size_t)b*61 + d)*N_ + n0 + t];
  __syncthreads();
  // coalesced padded write: thread t writes dim t of every row
  for (int r = 0; r < 64; ++r)
    pT[((size_t)b*N_ + n0 + r)*64 + t] = (t < 61) ? tile[t][r] : 0.f;
}

// ---------------- FPS: exact reproduction of reference scan ----------------
// 512 thr x 8 pts in named scalars; DPP two-phase wave reduce; single
// parity-buffered LDS slot round per iteration (R3-validated sync scheme).
#define REP8(M) M(0) M(1) M(2) M(3) M(4) M(5) M(6) M(7)

__global__ __launch_bounds__(512, 1) void fps_kernel(const float* __restrict__ xyz,
                                                     StartIdx st,
                                                     float* __restrict__ new_xyz,
                                                     float* __restrict__ out_xyz){
  const int b = blockIdx.x, tid = threadIdx.x;
  const int lane = tid & 63, wv = tid >> 6;       // 8 waves
  const float* xb = xyz + (size_t)b*3*N_;
  __shared__ float4 pts4[N_];                     // 64 KiB
  __shared__ unsigned long long slots[2][8];

#define LOADP(i) \
  float px##i = xb[tid + 512*(i)]; \
  float py##i = xb[N_ + tid + 512*(i)]; \
  float pz##i = xb[2*N_ + tid + 512*(i)]; \
  float dm##i = 1e10f; \
  pts4[tid + 512*(i)] = make_float4(px##i, py##i, pz##i, 0.f);
  REP8(LOADP)
#undef LOADP
  __syncthreads();

  const int start = st.v[b];
  float4 c4 = pts4[start];
  float cx = c4.x, cy = c4.y, cz = c4.z;

  int par = 0;
  for (int s = 0; s < S_; ++s){
    if (tid == 0){
      new_xyz[((size_t)b*S_ + s)*3 + 0] = cx;
      new_xyz[((size_t)b*S_ + s)*3 + 1] = cy;
      new_xyz[((size_t)b*S_ + s)*3 + 2] = cz;
      out_xyz[(size_t)b*3*S_ + s]        = cx;
      out_xyz[(size_t)b*3*S_ + S_ + s]   = cy;
      out_xyz[(size_t)b*3*S_ + 2*S_ + s] = cz;
    }
    // distance + dmin update (exact reference float semantics: rn ops, no FMA;
    // dm = sum of squares of subtractions => always >= 0)
#define UPD(i) { \
      float dx = __fsub_rn(px##i, cx), dy = __fsub_rn(py##i, cy), dz = __fsub_rn(pz##i, cz); \
      float d  = __fadd_rn(__fadd_rn(__fmul_rn(dx,dx), __fmul_rn(dy,dy)), __fmul_rn(dz,dz)); \
      dm##i = fminf(dm##i, d); }
    REP8(UPD)
#undef UPD
    // phase A: wave max of dmin (f32, DPP)
    float m01 = fmaxf(dm0, dm1), m23 = fmaxf(dm2, dm3);
    float m45 = fmaxf(dm4, dm5), m67 = fmaxf(dm6, dm7);
    float lmax = fmaxf(fmaxf(m01, m23), fmaxf(m45, m67));
    float wmax = dpp_wave_max_f32(lmax);
    // phase B: wave min index among dm == wmax (u32, DPP).
    // descending assignment order => smallest local index wins.
    unsigned cand = 0xFFFFFFFFu;
#define CAND(i) cand = (dm##i == wmax) ? (unsigned)(tid + 512*(i)) : cand;
    CAND(7) CAND(6) CAND(5) CAND(4) CAND(3) CAND(2) CAND(1) CAND(0)
#undef CAND
    unsigned widx = dpp_wave_min_u32(cand);
    // cross-wave: one u64 slot per wave; larger key wins = larger dmin, then
    // smaller index (via ~idx). Parity buffers keep one barrier per iter.
    if (lane == 63)
      slots[par][wv] = ((unsigned long long)__float_as_uint(wmax) << 32)
                     | (unsigned long long)(unsigned)(~widx);
    __syncthreads();
    unsigned long long bk = slots[par][0];
    { unsigned long long v1 = slots[par][1]; if (v1 > bk) bk = v1;
      unsigned long long v2 = slots[par][2]; if (v2 > bk) bk = v2;
      unsigned long long v3 = slots[par][3]; if (v3 > bk) bk = v3;
      unsigned long long v4 = slots[par][4]; if (v4 > bk) bk = v4;
      unsigned long long v5 = slots[par][5]; if (v5 > bk) bk = v5;
      unsigned long long v6 = slots[par][6]; if (v6 > bk) bk = v6;
      unsigned long long v7 = slots[par][7]; if (v7 > bk) bk = v7; }
    const int winner = (int)(~(unsigned)bk) & (N_ - 1);
    float4 w4 = pts4[winner];                    // broadcast read
    cx = w4.x; cy = w4.y; cz = w4.z;
    par ^= 1;
  }
}
#undef REP8

// ---------------- KNN: 32 smallest sqdist per query, wave per query --------
// u64 key = (ordf(dist)<<32) | idx  => min = smallest dist, ties lowest idx.
// dist LDS swizzled: element (row i, col j) at [i*64 + ((j+i)&63)] so the
// column rescan (fixed col, lane=row) is bank-conflict-free.
__global__ __launch_bounds__(256) void knn_kernel(const float* __restrict__ xyz,
                                                  const float* __restrict__ nxyz,
                                                  int* __restrict__ knn_idx){
  __shared__ float dist[4][4096];           // 64 KiB
  const int wv = threadIdx.x >> 6, lane = threadIdx.x & 63;
  const int q = blockIdx.x*4 + wv;          // 0..8191
  const int b = q >> 10;
  const float* xb = xyz + (size_t)b*3*N_;
  const float ax = nxyz[(size_t)q*3], ay = nxyz[(size_t)q*3+1], az = nxyz[(size_t)q*3+2];
  const float sa = __fadd_rn(__fadd_rn(__fmul_rn(ax,ax), __fmul_rn(ay,ay)), __fmul_rn(az,az));
  float* dw = dist[wv];
  unsigned long long kk = ~0ull;            // this lane's min key over its column set
  for (int i = 0; i < 64; ++i){
    int n = i*64 + lane;
    float x = xb[n], y = xb[N_+n], z = xb[2*N_+n];
    float sb  = __fadd_rn(__fadd_rn(__fmul_rn(x,x), __fmul_rn(y,y)), __fmul_rn(z,z));
    float dot = __fadd_rn(__fadd_rn(__fmul_rn(ax,x), __fmul_rn(ay,y)), __fmul_rn(az,z));
    float d   = __fsub_rn(__fadd_rn(sa, sb), __fmul_rn(2.f, dot));
    dw[i*64 + ((lane + i) & 63)] = d;       // swizzled store (perm within row)
    unsigned long long key = ((unsigned long long)ordf(d) << 32) | (unsigned)n;
    if (key < kk) kk = key;
  }
  __syncthreads();
  int myout = 0;
  for (int r = 0; r < 32; ++r){
    unsigned long long g = dpp_wave_min_u64(kk);     // broadcast global min
    const int gn = (int)(g & 0xFFFFFFFFull);
    if (lane == r) myout = gn;
    const int col = gn & 63, row = gn >> 6;
    // rescan extracted owner's column: lane plays row index
    const int a = lane*64 + ((col + lane) & 63);
    float v = dw[a];
    if (lane == row){ v = 3.4e38f; dw[a] = 3.4e38f; }
    unsigned long long nk = ((unsigned long long)ordf(v) << 32)
                          | (unsigned)(lane*64 + col);
    nk = dpp_wave_min_u64(nk);
    if (lane == col) kk = nk;               // owner's refreshed local min
  }
  if (lane < 32) knn_idx[(size_t)q*32 + lane] = myout;
}

// ---------------- MLP layer 0: gather + 64->64 + bias -> y [64][P] ---------
__global__ __launch_bounds__(256, 2) void m0_kernel(const float* __restrict__ pT,
                                                    const float* __restrict__ xyz,
                                                    const float* __restrict__ nxyz,
                                                    const int* __restrict__ knn_idx,
                                                    const float* __restrict__ w,
                                                    const float* __restrict__ bias,
                                                    float* __restrict__ y){
  __shared__ float Wt[4096]; __shared__ float bb[64];
  for (int t = threadIdx.x; t < 4096; t += 256){ int o = t >> 6, c = t & 63; Wt[c*64+o] = w[o*64+c]; }
  if (threadIdx.x < 64) bb[threadIdx.x] = bias[threadIdx.x];
  __syncthreads();
  const int p = blockIdx.x*256 + threadIdx.x;
  const int b = p >> 15, s = (p & 32767) >> 5;
  const int n = knn_idx[p];
  float in[64];
  {
    const float* xb = xyz + (size_t)b*3*N_;
    const int q = (b << 10) + s;
    in[0] = xb[n]       - nxyz[(size_t)q*3];
    in[1] = xb[N_+n]    - nxyz[(size_t)q*3+1];
    in[2] = xb[2*N_+n]  - nxyz[(size_t)q*3+2];
    const float* pr = pT + ((size_t)b*N_ + n)*64;   // 256B-aligned padded row
#pragma unroll
    for (int d = 0; d < 60; d += 4){
      float4 v = *reinterpret_cast<const float4*>(&pr[d]);
      in[3+d] = v.x; in[4+d] = v.y; in[5+d] = v.z; in[6+d] = v.w;
    }
    in[63] = pr[60];
  }
  float acc[64];
#pragma unroll
  for (int o = 0; o < 64; ++o) acc[o] = bb[o];
#pragma unroll
  for (int c = 0; c < 64; ++c){
    float x = in[c];
#pragma unroll
    for (int o = 0; o < 64; o += 4){
      float4 w4 = *reinterpret_cast<const float4*>(&Wt[c*64+o]);
      acc[o]   += x*w4.x; acc[o+1] += x*w4.y; acc[o+2] += x*w4.z; acc[o+3] += x*w4.w;
    }
  }
#pragma unroll
  for (int o = 0; o < 64; ++o) y[(size_t)o*P_ + p] = acc[o];
}

// ---------------- generic channel stats: sum & sumsq (double atomics) ------
__global__ __launch_bounds__(256) void stats_kernel(const float* __restrict__ y,
                                                    double* __restrict__ st, int C){
  const int c = blockIdx.x % C, chunk = blockIdx.x / C;   // 8 chunks of 32768
  const float4* row4 = reinterpret_cast<const float4*>(y + (size_t)c*P_ + (size_t)chunk*32768);
  double s = 0.0, q = 0.0;
  for (int i = threadIdx.x; i < 8192; i += 256){
    float4 v = row4[i];
    s += (double)v.x + (double)v.y + (double)v.z + (double)v.w;
    q += (double)v.x*v.x + (double)v.y*v.y + (double)v.z*v.z + (double)v.w*v.w;
  }
  __shared__ double ss[256], qq[256];
  ss[threadIdx.x] = s; qq[threadIdx.x] = q; __syncthreads();
  for (int w = 128; w >= 1; w >>= 1){
    if (threadIdx.x < w){ ss[threadIdx.x] += ss[threadIdx.x+w]; qq[threadIdx.x] += qq[threadIdx.x+w]; }
    __syncthreads();
  }
  if (threadIdx.x == 0){ atomicAdd(&st[c*2], ss[0]); atomicAdd(&st[c*2+1], qq[0]); }
}

// helper: BN scale/shift from stats
__device__ __forceinline__ void bn_coeff(const double* st, const float* g, const float* be,
                                         int c, double cnt, float* sc, float* sh){
  double mean = st[c*2] / cnt;
  double var  = st[c*2+1] / cnt - mean*mean;
  double scale = (double)g[c] / sqrt(var + 1e-5);
  *sc = (float)scale; *sh = (float)((double)be[c] - mean*scale);
}

// ---------------- MLP layer 1: bn(relu) then 64->64, in place --------------
__global__ __launch_bounds__(256, 2) void m1_kernel(float* __restrict__ y,
                                                    const float* __restrict__ w,
                                                    const float* __restrict__ bias,
                                                    const double* __restrict__ st,
                                                    const float* __restrict__ g,
                                                    const float* __restrict__ be){
  __shared__ float Wt[4096]; __shared__ float bb[64], sc[64], sh[64];
  for (int t = threadIdx.x; t < 4096; t += 256){ int o = t >> 6, c = t & 63; Wt[c*64+o] = w[o*64+c]; }
  if (threadIdx.x < 64){
    bn_coeff(st, g, be, threadIdx.x, (double)P_, &sc[threadIdx.x], &sh[threadIdx.x]);
    bb[threadIdx.x] = bias[threadIdx.x];
  }
  __syncthreads();
  const int p = blockIdx.x*256 + threadIdx.x;
  float in[64];
#pragma unroll
  for (int c = 0; c < 64; ++c){
    float x = y[(size_t)c*P_ + p];
    in[c] = fmaxf(0.f, fmaf(x, sc[c], sh[c]));
  }
  float acc[64];
#pragma unroll
  for (int o = 0; o < 64; ++o) acc[o] = bb[o];
#pragma unroll
  for (int c = 0; c < 64; ++c){
    float x = in[c];
#pragma unroll
    for (int o = 0; o < 64; o += 4){
      float4 w4 = *reinterpret_cast<const float4*>(&Wt[c*64+o]);
      acc[o]   += x*w4.x; acc[o+1] += x*w4.y; acc[o+2] += x*w4.z; acc[o+3] += x*w4.w;
    }
  }
#pragma unroll
  for (int o = 0; o < 64; ++o) y[(size_t)o*P_ + p] = acc[o];
}

// ---------------- MLP layer 2: bn(relu) then 64->128 (half per blockIdx.y) -
__global__ __launch_bounds__(256, 2) void m2_kernel(const float* __restrict__ y1,
                                                    float* __restrict__ y2,
                                                    const float* __restrict__ w,
                                                    const float* __restrict__ bias,
                                                    const double* __restrict__ st,
                                                    const float* __restrict__ g,
                                                    const float* __restrict__ be){
  __shared__ float Wt[4096]; __shared__ float bb[64], sc[64], sh[64];
  const int half = blockIdx.y;
  for (int t = threadIdx.x; t < 4096; t += 256){
    int o = t >> 6, c = t & 63;
    Wt[c*64+o] = w[(size_t)(half*64+o)*64 + c];
  }
  if (threadIdx.x < 64){
    bn_coeff(st, g, be, threadIdx.x, (double)P_, &sc[threadIdx.x], &sh[threadIdx.x]);
    bb[threadIdx.x] = bias[half*64 + threadIdx.x];
  }
  __syncthreads();
  const int p = blockIdx.x*256 + threadIdx.x;
  float in[64];
#pragma unroll
  for (int c = 0; c < 64; ++c){
    float x = y1[(size_t)c*P_ + p];
    in[c] = fmaxf(0.f, fmaf(x, sc[c], sh[c]));
  }
  float acc[64];
#pragma unroll
  for (int o = 0; o < 64; ++o) acc[o] = bb[o];
#pragma unroll
  for (int c = 0; c < 64; ++c){
    float x = in[c];
#pragma unroll
    for (int o = 0; o < 64; o += 4){
      float4 w4 = *reinterpret_cast<const float4*>(&Wt[c*64+o]);
      acc[o]   += x*w4.x; acc[o+1] += x*w4.y; acc[o+2] += x*w4.z; acc[o+3] += x*w4.w;
    }
  }
#pragma unroll
  for (int o = 0; o < 64; ++o) y2[(size_t)(half*64+o)*P_ + p] = acc[o];
}

// ---------------- WeightNet layer 0: gather g_norm, 3->8 ------------------
__global__ __launch_bounds__(256) void w0_kernel(const float* __restrict__ xyz,
                                                 const float* __restrict__ nxyz,
                                                 const int* __restrict__ knn_idx,
                                                 const float* __restrict__ w,   // [8][3]
                                                 const float* __restrict__ bias,
                                                 float* __restrict__ wb){
  __shared__ float Wl[24], bb[8];
  if (threadIdx.x < 24) Wl[threadIdx.x] = w[threadIdx.x];
  if (threadIdx.x < 8)  bb[threadIdx.x] = bias[threadIdx.x];
  __syncthreads();
  const int p = blockIdx.x*256 + threadIdx.x;
  const int b = p >> 15, s = (p & 32767) >> 5;
  const int n = knn_idx[p];
  const float* xb = xyz + (size_t)b*3*N_;
  const int q = (b << 10) + s;
  float gx = xb[n]      - nxyz[(size_t)q*3];
  float gy = xb[N_+n]   - nxyz[(size_t)q*3+1];
  float gz = xb[2*N_+n] - nxyz[(size_t)q*3+2];
#pragma unroll
  for (int o = 0; o < 8; ++o){
    float a = bb[o] + gx*Wl[o*3] + gy*Wl[o*3+1] + gz*Wl[o*3+2];
    wb[(size_t)o*P_ + p] = a;
  }
}

// ---------------- WeightNet layer 1: bn relu 8->8 in place ----------------
__global__ __launch_bounds__(256) void w1_kernel(float* __restrict__ wb,
                                                 const float* __restrict__ w,   // [8][8]
                                                 const float* __restrict__ bias,
                                                 const double* __restrict__ st,
                                                 const float* __restrict__ g,
                                                 const float* __restrict__ be){
  __shared__ float Wl[64], bb[8], sc[8], sh[8];
  if (threadIdx.x < 64) Wl[threadIdx.x] = w[threadIdx.x];
  if (threadIdx.x < 8){
    bn_coeff(st, g, be, threadIdx.x, (double)P_, &sc[threadIdx.x], &sh[threadIdx.x]);
    bb[threadIdx.x] = bias[threadIdx.x];
  }
  __syncthreads();
  const int p = blockIdx.x*256 + threadIdx.x;
  float in[8];
#pragma unroll
  for (int c = 0; c < 8; ++c){
    float x = wb[(size_t)c*P_ + p];
    in[c] = fmaxf(0.f, fmaf(x, sc[c], sh[c]));
  }
  float acc[8];
#pragma unroll
  for (int o = 0; o < 8; ++o){
    float a = bb[o];
#pragma unroll
    for (int c = 0; c < 8; ++c) a += in[c]*Wl[o*8+c];
    acc[o] = a;
  }
#pragma unroll
  for (int o = 0; o < 8; ++o) wb[(size_t)o*P_ + p] = acc[o];
}

// ---------------- WeightNet layer 2: bn relu 8->16 ------------------------
__global__ __launch_bounds__(256) void w2_kernel(const float* __restrict__ wb,
                                                 float* __restrict__ wb2,
                                                 const float* __restrict__ w,   // [16][8]
                                                 const float* __restrict__ bias,
                                                 const double* __restrict__ st,
                                                 const float* __restrict__ g,
                                                 const float* __restrict__ be){
  __shared__ float Wl[128], bb[16], sc[8], sh[8];
  if (threadIdx.x < 128) Wl[threadIdx.x] = w[threadIdx.x];
  if (threadIdx.x < 8)
    bn_coeff(st, g, be, threadIdx.x, (double)P_, &sc[threadIdx.x], &sh[threadIdx.x]);
  if (threadIdx.x < 16) bb[threadIdx.x] = bias[threadIdx.x];
  __syncthreads();
  const int p = blockIdx.x*256 + threadIdx.x;
  float in[8];
#pragma unroll
  for (int c = 0; c < 8; ++c){
    float x = wb[(size_t)c*P_ + p];
    in[c] = fmaxf(0.f, fmaf(x, sc[c], sh[c]));
  }
#pragma unroll
  for (int o = 0; o < 16; ++o){
    float a = bb[o];
#pragma unroll
    for (int c = 0; c < 8; ++c) a += in[c]*Wl[o*8+c];
    wb2[(size_t)o*P_ + p] = a;
  }
}

// ---------------- agg: per (b,s) [128,K]x[K,16] -> agg row [2048] ----------
__global__ __launch_bounds__(256) void agg_kernel(const float* __restrict__ y2,
                                                  const float* __restrict__ wb2,
                                                  const double* __restrict__ st2,
                                                  const float* __restrict__ g2,
                                                  const float* __restrict__ be2,
                                                  const double* __restrict__ stw,
                                                  const float* __restrict__ gw,
                                                  const float* __restrict__ bew,
                                                  float* __restrict__ agg){
  __shared__ float f[32*132];      // [k][c] padded
  __shared__ float wt[32*16];      // [k][w]
  __shared__ float sc2[128], sh2[128], scw[16], shw[16];
  const int t = threadIdx.x;
  if (t < 128) bn_coeff(st2, g2, be2, t, (double)P_, &sc2[t], &sh2[t]);
  if (t < 16)  bn_coeff(stw, gw, bew, t, (double)P_, &scw[t], &shw[t]);
  __syncthreads();
  const int bs = blockIdx.x;
  const size_t p0 = (size_t)bs * 32;
  for (int e = t; e < 4096; e += 256){
    int c = e >> 5, k = e & 31;
    float x = y2[(size_t)c*P_ + p0 + k];
    f[k*132 + c] = fmaxf(0.f, fmaf(x, sc2[c], sh2[c]));
  }
  for (int e = t; e < 512; e += 256){
    int w = e >> 5, k = e & 31;
    float x = wb2[(size_t)w*P_ + p0 + k];
    wt[k*16 + w] = fmaxf(0.f, fmaf(x, scw[w], shw[w]));
  }
  __syncthreads();
  const int c = t >> 1, wp = (t & 1) * 8;
  float a0=0,a1=0,a2=0,a3=0,a4=0,a5=0,a6=0,a7=0;
#pragma unroll
  for (int k = 0; k < 32; ++k){
    float fv = f[k*132 + c];
    float4 u = *reinterpret_cast<const float4*>(&wt[k*16 + wp]);
    float4 v = *reinterpret_cast<const float4*>(&wt[k*16 + wp + 4]);
    a0 += fv*u.x; a1 += fv*u.y; a2 += fv*u.z; a3 += fv*u.w;
    a4 += fv*v.x; a5 += fv*v.y; a6 += fv*v.z; a7 += fv*v.w;
  }
  float* dst = agg + (size_t)bs*2048 + c*16 + wp;
  *reinterpret_cast<float4*>(dst)     = make_float4(a0,a1,a2,a3);
  *reinterpret_cast<float4*>(dst + 4) = make_float4(a4,a5,a6,a7);
}

// ---------------- linear GEMM: [8192,2048] x [128,2048]^T + b --------------
__global__ __launch_bounds__(256) void lin_kernel(const float* __restrict__ agg,
                                                  const float* __restrict__ lw,
                                                  const float* __restrict__ lb,
                                                  float* __restrict__ outp){
  __shared__ float A[32*33];        // [r][kk] padded
  __shared__ float Wl[32*128];      // [kk][o]
  __shared__ float lbs[128];
  const int t = threadIdx.x;
  const int r0 = blockIdx.x * 32;
  if (t < 128) lbs[t] = lb[t];
  const int c_lane = t & 31, rg = t >> 5;
  float acc[4][4];
#pragma unroll
  for (int i = 0; i < 4; ++i)
#pragma unroll
    for (int j = 0; j < 4; ++j) acc[i][j] = 0.f;

  for (int kk0 = 0; kk0 < 2048; kk0 += 32){
    __syncthreads();
    {
      int r = t >> 3, kq = (t & 7) * 4;
      float4 v = *reinterpret_cast<const float4*>(&agg[(size_t)(r0 + r)*2048 + kk0 + kq]);
      A[r*33 + kq]   = v.x; A[r*33 + kq+1] = v.y; A[r*33 + kq+2] = v.z; A[r*33 + kq+3] = v.w;
    }
    {
#pragma unroll
      for (int u = 0; u < 4; ++u){
        int fid = t + 256*u;
        int o = fid >> 3, kq = (fid & 7) * 4;
        float4 v = *reinterpret_cast<const float4*>(&lw[(size_t)o*2048 + kk0 + kq]);
        Wl[(kq  )*128 + o] = v.x; Wl[(kq+1)*128 + o] = v.y;
        Wl[(kq+2)*128 + o] = v.z; Wl[(kq+3)*128 + o] = v.w;
      }
    }
    __syncthreads();
#pragma unroll 8
    for (int kk = 0; kk < 32; ++kk){
      float a0 = A[(rg*4+0)*33 + kk], a1 = A[(rg*4+1)*33 + kk],
            a2 = A[(rg*4+2)*33 + kk], a3 = A[(rg*4+3)*33 + kk];
#pragma unroll
      for (int j = 0; j < 4; ++j){
        float wv = Wl[kk*128 + c_lane + 32*j];
        acc[0][j] += a0*wv; acc[1][j] += a1*wv; acc[2][j] += a2*wv; acc[3][j] += a3*wv;
      }
    }
  }
  __syncthreads();
#pragma unroll
  for (int i = 0; i < 4; ++i)
#pragma unroll
    for (int j = 0; j < 4; ++j){
      int o = c_lane + 32*j;
      outp[(size_t)(r0 + rg*4 + i)*128 + o] = acc[i][j] + lbs[o];
    }
}

// ---------------- final BN stats over (b,s) --------------------------------
__global__ __launch_bounds__(128) void statsF_kernel(const float* __restrict__ outp,
                                                     double* __restrict__ st){
  const int c = threadIdx.x;
  const int r0 = blockIdx.x * 128;
  double s = 0.0, q = 0.0;
  for (int r = 0; r < 128; ++r){
    double v = outp[(size_t)(r0 + r)*128 + c];
    s += v; q += v*v;
  }
  atomicAdd(&st[c*2], s); atomicAdd(&st[c*2+1], q);
}

// ---------------- final BN+relu + transpose to [B,128,S] -------------------
__global__ __launch_bounds__(256) void final_kernel(const float* __restrict__ outp,
                                                    const double* __restrict__ st,
                                                    const float* __restrict__ g,
                                                    const float* __restrict__ be,
                                                    float* __restrict__ out){
  const int gid = blockIdx.x*256 + threadIdx.x;     // b*131072 + o*1024 + s
  const int s = gid & 1023, o = (gid >> 10) & 127, b = gid >> 17;
  float sc, sh;
  bn_coeff(st, g, be, o, (double)BS_, &sc, &sh);
  float x = outp[((size_t)(b << 10) + s)*128 + o];
  out[gid] = fmaxf(0.f, fmaf(x, sc, sh));
}

// ---------------------------------------------------------------------------
extern "C" void kernel_launch(void* const* d_in, const int* in_sizes, int n_in,
                              void* d_out, int out_size, void* d_ws, size_t ws_size,
                              hipStream_t stream){
  (void)in_sizes; (void)n_in; (void)out_size; (void)ws_size;
  const float* xyz    = (const float*)d_in[0];
  const float* points = (const float*)d_in[1];
  const float* mw0 = (const float*)d_in[2],  *mb0 = (const float*)d_in[3],
             * mg0 = (const float*)d_in[4],  *me0 = (const float*)d_in[5];
  const float* mw1 = (const float*)d_in[6],  *mb1 = (const float*)d_in[7],
             * mg1 = (const float*)d_in[8],  *me1 = (const float*)d_in[9];
  const float* mw2 = (const float*)d_in[10], *mb2 = (const float*)d_in[11],
             * mg2 = (const float*)d_in[12], *me2 = (const float*)d_in[13];
  const float* ww0 = (const float*)d_in[14], *wb0 = (const float*)d_in[15],
             * wg0 = (const float*)d_in[16], *we0 = (const float*)d_in[17];
  const float* ww1 = (const float*)d_in[18], *wb1 = (const float*)d_in[19],
             * wg1 = (const float*)d_in[20], *we1 = (const float*)d_in[21];
  const float* ww2 = (const float*)d_in[22], *wb2_ = (const float*)d_in[23],
             * wg2 = (const float*)d_in[24], *we2 = (const float*)d_in[25];
  const float* lw  = (const float*)d_in[26], *lb  = (const float*)d_in[27];
  const float* fg  = (const float*)d_in[28], *fb  = (const float*)d_in[29];

  char* ws = (char*)d_ws;
  double* ST0 = (double*)(ws + OFF_STATS);
  double* ST1 = (double*)(ws + OFF_STATS + 1024);
  double* ST2 = (double*)(ws + OFF_STATS + 2048);
  double* SW0 = (double*)(ws + OFF_STATS + 4096);
  double* SW1 = (double*)(ws + OFF_STATS + 4224);
  double* SW2 = (double*)(ws + OFF_STATS + 4352);
  double* STF = (double*)(ws + OFF_STATS + 4608);
  float* nxyz   = (float*)(ws + OFF_NEWXYZ);
  int*   knnidx = (int*)(ws + OFF_KNN);
  float* pT     = (float*)(ws + OFF_PT);
  float* y01    = (float*)(ws + OFF_Y01);
  float* y2     = (float*)(ws + OFF_Y2);
  float* w01    = (float*)(ws + OFF_W01);
  float* w2b    = (float*)(ws + OFF_W2B);
  float* aggbuf = (float*)(ws + OFF_Y01);   // alias: y01 dead after m2
  float* outpre = (float*)(ws + OFF_OUTPRE);// alias: w01 dead after w2

  float* out_xyz  = (float*)d_out;                      // [B,3,S]
  float* out_feat = (float*)d_out + (size_t)B_*3*S_;    // [B,128,S]

  hipMemsetAsync(ws + OFF_STATS, 0, 8192, stream);

  tr_kernel<<<dim3(B_*64), dim3(64), 0, stream>>>(points, pT);

  StartIdx st = compute_starts();
  fps_kernel<<<dim3(B_), dim3(512), 0, stream>>>(xyz, st, nxyz, out_xyz);

  knn_kernel<<<dim3(BS_/4), dim3(256), 0, stream>>>(xyz, nxyz, knnidx);

  m0_kernel<<<dim3(P_/256), dim3(256), 0, stream>>>(pT, xyz, nxyz, knnidx, mw0, mb0, y01);
  stats_kernel<<<dim3(64*8), dim3(256), 0, stream>>>(y01, ST0, 64);
  m1_kernel<<<dim3(P_/256), dim3(256), 0, stream>>>(y01, mw1, mb1, ST0, mg0, me0);
  stats_kernel<<<dim3(64*8), dim3(256), 0, stream>>>(y01, ST1, 64);
  m2_kernel<<<dim3(P_/256, 2), dim3(256), 0, stream>>>(y01, y2, mw2, mb2, ST1, mg1, me1);
  stats_kernel<<<dim3(128*8), dim3(256), 0, stream>>>(y2, ST2, 128);

  w0_kernel<<<dim3(P_/256), dim3(256), 0, stream>>>(xyz, nxyz, knnidx, ww0, wb0, w01);
  stats_kernel<<<dim3(8*8), dim3(256), 0, stream>>>(w01, SW0, 8);
  w1_kernel<<<dim3(P_/256), dim3(256), 0, stream>>>(w01, ww1, wb1, SW0, wg0, we0);
  stats_kernel<<<dim3(8*8), dim3(256), 0, stream>>>(w01, SW1, 8);
  w2_kernel<<<dim3(P_/256), dim3(256), 0, stream>>>(w01, w2b, ww2, wb2_, SW1, wg1, we1);
  stats_kernel<<<dim3(16*8), dim3(256), 0, stream>>>(w2b, SW2, 16);

  agg_kernel<<<dim3(BS_), dim3(256), 0, stream>>>(y2, w2b, ST2, mg2, me2, SW2, wg2, we2, aggbuf);
  lin_kernel<<<dim3(BS_/32), dim3(256), 0, stream>>>(aggbuf, lw, lb, outpre);
  statsF_kernel<<<dim3(BS_/128), dim3(128), 0, stream>>>(outpre, STF);
  final_kernel<<<dim3((B_*128*S_)/256), dim3(256), 0, stream>>>(outpre, STF, fg, fb, out_feat);
}

// Round 5
// 1542.810 us; speedup vs baseline: 3.2652x; 1.0101x over previous
//
#include <hip/hip_runtime.h>
#include <cstdint>
#include <cstddef>

// ---------------------------------------------------------------------------
// PointConv Set Abstraction forward, MI355X (gfx950).
// B=8, N=4096, D=61, S=1024, K=32; MLP 64->64->64->128 ; WeightNet 3->8->8->16
// Output: concat( new_xyz [B,3,S], out [B,128,S] ) fp32.
// R5: (a) fps loop has NO global memory ops (winner u16 ring in LDS, outputs
//     written in epilogue) -- R4 post-mortem: s_waitcnt vmcnt(0) before each
//     s_barrier drained tid0's per-iter global stores, stalling all 8 waves.
//     Single-chain u64 DPP max replaces two-phase reduce. (b) transpose fused
//     into fps grid (blocks >= 8, runs on idle CUs). (c) BN stats fused into
//     producer kernels (DPP row sums + f64 agent-scope atomics): 6 stats
//     dispatches and ~350MB of re-reads removed. (d) final_kernel: per-block
//     BN coeffs + LDS-transposed coalesced access.
// ---------------------------------------------------------------------------

constexpr int B_ = 8, N_ = 4096, D_ = 61, S_ = 1024, K_ = 32;
constexpr int P_ = B_ * S_ * K_;          // 262144 positions (b,s,k)
constexpr int BS_ = B_ * S_;              // 8192

// ---------------- workspace layout (bytes) ----------------
constexpr size_t OFF_STATS  = 0;                          // 8192 B, zeroed
constexpr size_t OFF_NEWXYZ = 8192;                       // [B*S][3] f32
constexpr size_t OFF_KNN    = 106496;                     // [P] int
constexpr size_t OFF_PT     = 1155072;                    // [B*N][64] f32 padded
constexpr size_t OFF_Y01    = 9543680;                    // [64][P] f32 (also aggbuf alias)
constexpr size_t OFF_Y2     = 76652544;                   // [128][P] f32
constexpr size_t OFF_W01    = 210870272;                  // [8][P] f32 (outpre alias after dead)
constexpr size_t OFF_W2B    = 219258880;                  // [16][P] f32
constexpr size_t OFF_OUTPRE = OFF_W01;                    // [8192][128] f32 (w01 dead by lin)

// ---------------- host threefry (JAX PRNG reproduction) ----------------
static inline uint32_t rotl32(uint32_t x, int r){ return (x << r) | (x >> (32 - r)); }
static void tf2x32(uint32_t k0, uint32_t k1, uint32_t x0, uint32_t x1,
                   uint32_t* o0, uint32_t* o1){
  uint32_t ks[3] = {k0, k1, k0 ^ k1 ^ 0x1BD11BDAu};
  x0 += ks[0]; x1 += ks[1];
  const int RA[4] = {13,15,26,6}, RB[4] = {17,29,16,24};
  for (int i = 0; i < 5; ++i){
    const int* R = (i & 1) ? RB : RA;
    for (int j = 0; j < 4; ++j){ x0 += x1; x1 = rotl32(x1, R[j]); x1 ^= x0; }
    x0 += ks[(i+1)%3]; x1 += ks[(i+2)%3] + (uint32_t)(i+1);
  }
  *o0 = x0; *o1 = x1;
}
struct StartIdx { int v[8]; };
static StartIdx compute_starts(){
  uint32_t ka, kb;
  tf2x32(0u, 42u, 0u, 1u, &ka, &kb);          // split(key)[1]
  StartIdx s;
  for (int i = 0; i < 8; ++i){
    uint32_t b1, b2;
    tf2x32(ka, kb, 0u, (uint32_t)i, &b1, &b2);
    s.v[i] = (int)((b1 ^ b2) & 4095u);        // MODE 1 (validated in R1)
  }
  return s;
}

// ---------------- DPP helpers (wave64) ----------------
template<int C>
__device__ __forceinline__ unsigned long long dpp_max_u64_step(unsigned long long k){
  unsigned lo = (unsigned)k, hi = (unsigned)(k >> 32);
  unsigned olo = (unsigned)__builtin_amdgcn_update_dpp(0, (int)lo, C, 0xf, 0xf, true);
  unsigned ohi = (unsigned)__builtin_amdgcn_update_dpp(0, (int)hi, C, 0xf, 0xf, true);
  unsigned long long o = ((unsigned long long)ohi << 32) | olo;
  return o > k ? o : k;    // identity 0 valid: keys have hi bit 31 = 0 (dm>=0)
}
__device__ __forceinline__ unsigned long long dpp_wave_max_u64(unsigned long long k){
  k = dpp_max_u64_step<0x111>(k);
  k = dpp_max_u64_step<0x112>(k);
  k = dpp_max_u64_step<0x114>(k);
  k = dpp_max_u64_step<0x118>(k);
  k = dpp_max_u64_step<0x142>(k);
  k = dpp_max_u64_step<0x143>(k);
  return k;                // lane 63 holds the wave max
}
template<int C>
__device__ __forceinline__ unsigned long long dpp_min_u64_step(unsigned long long k){
  unsigned lo = (unsigned)k, hi = (unsigned)(k >> 32);
  unsigned olo = (unsigned)__builtin_amdgcn_update_dpp(-1, (int)lo, C, 0xf, 0xf, false);
  unsigned ohi = (unsigned)__builtin_amdgcn_update_dpp(-1, (int)hi, C, 0xf, 0xf, false);
  unsigned long long o = ((unsigned long long)ohi << 32) | olo;
  return o < k ? o : k;
}
__device__ __forceinline__ unsigned long long dpp_wave_min_u64(unsigned long long k){
  k = dpp_min_u64_step<0x111>(k);
  k = dpp_min_u64_step<0x112>(k);
  k = dpp_min_u64_step<0x114>(k);
  k = dpp_min_u64_step<0x118>(k);
  k = dpp_min_u64_step<0x142>(k);
  k = dpp_min_u64_step<0x143>(k);
  unsigned lo = (unsigned)__builtin_amdgcn_readlane((int)(unsigned)k, 63);
  unsigned hi = (unsigned)__builtin_amdgcn_readlane((int)(unsigned)(k >> 32), 63);
  return ((unsigned long long)hi << 32) | lo;
}
template<int C>
__device__ __forceinline__ float dpp_add_step(float x){
  int t = __builtin_amdgcn_update_dpp(0, (int)__float_as_uint(x), C, 0xf, 0xf, true);
  return x + __uint_as_float((unsigned)t);
}
// after 4 shr steps, lane 15 of each row-of-16 holds that row's sum
__device__ __forceinline__ float dpp_row_sum16(float x){
  x = dpp_add_step<0x111>(x);
  x = dpp_add_step<0x112>(x);
  x = dpp_add_step<0x114>(x);
  x = dpp_add_step<0x118>(x);
  return x;
}
// order-preserving float->uint (handles negatives; ascending)
__device__ __forceinline__ unsigned ordf(float f){
  unsigned u = __float_as_uint(f);
  return u ^ (unsigned)(((int)u >> 31) | 0x80000000);
}
__device__ __forceinline__ void atomAddD(double* p, double v){
  __hip_atomic_fetch_add(p, v, __ATOMIC_RELAXED, __HIP_MEMORY_SCOPE_AGENT);
}

// ---------------- fused FPS (blocks 0..7) + transpose (blocks 8..519) ------
#define REP8(M) M(0) M(1) M(2) M(3) M(4) M(5) M(6) M(7)

__global__ __launch_bounds__(512, 1) void fps_tr_kernel(const float* __restrict__ xyz,
                                                        const float* __restrict__ pts,
                                                        StartIdx st,
                                                        float* __restrict__ new_xyz,
                                                        float* __restrict__ out_xyz,
                                                        float* __restrict__ pT){
  __shared__ float4 pts4[N_];                     // 64 KiB (tr: aliased tile)
  __shared__ unsigned short win[S_];              // 2 KiB winner ring
  __shared__ unsigned long long slots[2][8];
  const int tid = threadIdx.x;

  if (blockIdx.x >= 8){
    // ---- transpose tile: [B,61,N] -> [B][N][64] padded ----
    float* tile = (float*)pts4;                   // [61][65]
    const int tt = blockIdx.x - 8;
    const int b = tt >> 6, n0 = (tt & 63) * 64;
    for (int e = tid; e < 61*64; e += 512){
      int d = e >> 6, c = e & 63;
      tile[d*65 + c] = pts[((size_t)b*61 + d)*N_ + n0 + c];
    }
    __syncthreads();
    for (int e = tid; e < 4096; e += 512){
      int r = e >> 6, d = e & 63;
      pT[((size_t)b*N_ + n0 + r)*64 + d] = (d < 61) ? tile[d*65 + r] : 0.f;
    }
    return;
  }

  // ---- FPS: exact reproduction of reference scan ----
  const int b = blockIdx.x;
  const int lane = tid & 63, wv = tid >> 6;       // 8 waves
  const float* xb = xyz + (size_t)b*3*N_;

#define LOADP(i) \
  float px##i = xb[tid + 512*(i)]; \
  float py##i = xb[N_ + tid + 512*(i)]; \
  float pz##i = xb[2*N_ + tid + 512*(i)]; \
  float dm##i = 1e10f; \
  const unsigned kl##i = ~(unsigned)(tid + 512*(i)); \
  pts4[tid + 512*(i)] = make_float4(px##i, py##i, pz##i, 0.f);
  REP8(LOADP)
#undef LOADP
  __syncthreads();

  int cur = st.v[b];
  float4 c4 = pts4[cur];
  float cx = c4.x, cy = c4.y, cz = c4.z;

  int par = 0;
  for (int s = 0; s < S_; ++s){
    if (tid == 0) win[s] = (unsigned short)cur;   // LDS only, cheap
    if (s == S_ - 1) break;
    // distance + dmin update (exact reference float semantics: rn ops, no FMA)
#define UPD(i) \
    unsigned long long key##i; { \
      float dx = __fsub_rn(px##i, cx), dy = __fsub_rn(py##i, cy), dz = __fsub_rn(pz##i, cz); \
      float d  = __fadd_rn(__fadd_rn(__fmul_rn(dx,dx), __fmul_rn(dy,dy)), __fmul_rn(dz,dz)); \
      dm##i = fminf(dm##i, d); \
      key##i = ((unsigned long long)__float_as_uint(dm##i) << 32) | kl##i; }
    REP8(UPD)
#undef UPD
    // tree max over 8 u64 keys (max dmin, then min index via ~idx)
    unsigned long long t0 = key0 > key1 ? key0 : key1;
    unsigned long long t1 = key2 > key3 ? key2 : key3;
    unsigned long long t2 = key4 > key5 ? key4 : key5;
    unsigned long long t3 = key6 > key7 ? key6 : key7;
    unsigned long long u0 = t0 > t1 ? t0 : t1;
    unsigned long long u1 = t2 > t3 ? t2 : t3;
    unsigned long long k  = u0 > u1 ? u0 : u1;
    // single 6-step DPP wave max (lane 63 valid)
    k = dpp_wave_max_u64(k);
    if (lane == 63) slots[par][wv] = k;
    __syncthreads();
    unsigned long long bk = slots[par][0];
    { unsigned long long v1 = slots[par][1]; if (v1 > bk) bk = v1;
      unsigned long long v2 = slots[par][2]; if (v2 > bk) bk = v2;
      unsigned long long v3 = slots[par][3]; if (v3 > bk) bk = v3;
      unsigned long long v4 = slots[par][4]; if (v4 > bk) bk = v4;
      unsigned long long v5 = slots[par][5]; if (v5 > bk) bk = v5;
      unsigned long long v6 = slots[par][6]; if (v6 > bk) bk = v6;
      unsigned long long v7 = slots[par][7]; if (v7 > bk) bk = v7; }
    cur = (int)(~(unsigned)bk) & (N_ - 1);
    float4 w4 = pts4[cur];                        // broadcast read
    cx = w4.x; cy = w4.y; cz = w4.z;
    par ^= 1;
  }
  __syncthreads();
  // epilogue: all output writes at once
  for (int s2 = tid; s2 < S_; s2 += 512){
    float4 p = pts4[win[s2]];
    new_xyz[((size_t)b*S_ + s2)*3 + 0] = p.x;
    new_xyz[((size_t)b*S_ + s2)*3 + 1] = p.y;
    new_xyz[((size_t)b*S_ + s2)*3 + 2] = p.z;
    out_xyz[(size_t)b*3*S_ + s2]        = p.x;
    out_xyz[(size_t)b*3*S_ + S_ + s2]   = p.y;
    out_xyz[(size_t)b*3*S_ + 2*S_ + s2] = p.z;
  }
}
#undef REP8

// ---------------- KNN: 32 smallest sqdist per query, wave per query --------
__global__ __launch_bounds__(256) void knn_kernel(const float* __restrict__ xyz,
                                                  const float* __restrict__ nxyz,
                                                  int* __restrict__ knn_idx){
  __shared__ float dist[4][4096];           // 64 KiB
  const int wv = threadIdx.x >> 6, lane = threadIdx.x & 63;
  const int q = blockIdx.x*4 + wv;          // 0..8191
  const int b = q >> 10;
  const float* xb = xyz + (size_t)b*3*N_;
  const float ax = nxyz[(size_t)q*3], ay = nxyz[(size_t)q*3+1], az = nxyz[(size_t)q*3+2];
  const float sa = __fadd_rn(__fadd_rn(__fmul_rn(ax,ax), __fmul_rn(ay,ay)), __fmul_rn(az,az));
  float* dw = dist[wv];
  unsigned long long kk = ~0ull;
  for (int i = 0; i < 64; ++i){
    int n = i*64 + lane;
    float x = xb[n], y = xb[N_+n], z = xb[2*N_+n];
    float sb  = __fadd_rn(__fadd_rn(__fmul_rn(x,x), __fmul_rn(y,y)), __fmul_rn(z,z));
    float dot = __fadd_rn(__fadd_rn(__fmul_rn(ax,x), __fmul_rn(ay,y)), __fmul_rn(az,z));
    float d   = __fsub_rn(__fadd_rn(sa, sb), __fmul_rn(2.f, dot));
    dw[i*64 + ((lane + i) & 63)] = d;       // swizzled store
    unsigned long long key = ((unsigned long long)ordf(d) << 32) | (unsigned)n;
    if (key < kk) kk = key;
  }
  __syncthreads();
  int myout = 0;
  for (int r = 0; r < 32; ++r){
    unsigned long long g = dpp_wave_min_u64(kk);
    const int gn = (int)(g & 0xFFFFFFFFull);
    if (lane == r) myout = gn;
    const int col = gn & 63, row = gn >> 6;
    const int a = lane*64 + ((col + lane) & 63);
    float v = dw[a];
    if (lane == row){ v = 3.4e38f; dw[a] = 3.4e38f; }
    unsigned long long nk = ((unsigned long long)ordf(v) << 32)
                          | (unsigned)(lane*64 + col);
    nk = dpp_wave_min_u64(nk);
    if (lane == col) kk = nk;
  }
  if (lane < 32) knn_idx[(size_t)q*32 + lane] = myout;
}

// helper: BN scale/shift from stats
__device__ __forceinline__ void bn_coeff(const double* st, const float* g, const float* be,
                                         int c, double cnt, float* sc, float* sh){
  double mean = st[c*2] / cnt;
  double var  = st[c*2+1] / cnt - mean*mean;
  double scale = (double)g[c] / sqrt(var + 1e-5);
  *sc = (float)scale; *sh = (float)((double)be[c] - mean*scale);
}

// fused 64-channel stats epilogue (256-thread block): per-row16 DPP sums ->
// LDS -> f64 atomics. redS/redQ are [16][65] padded.
#define STATS64(ACC_EXPR, ST, CH_OFF)                                          \
  {                                                                            \
    _Pragma("unroll")                                                          \
    for (int o = 0; o < 64; ++o){                                              \
      float v_ = (ACC_EXPR);                                                   \
      float s1_ = dpp_row_sum16(v_);                                           \
      float q1_ = dpp_row_sum16(v_*v_);                                        \
      if ((threadIdx.x & 15) == 15){                                           \
        int rid_ = threadIdx.x >> 4;                                           \
        redS[rid_][o] = s1_; redQ[rid_][o] = q1_;                              \
      }                                                                        \
    }                                                                          \
    __syncthreads();                                                           \
    if (threadIdx.x < 64){                                                     \
      float s_ = 0.f;                                                          \
      _Pragma("unroll")                                                        \
      for (int r_ = 0; r_ < 16; ++r_) s_ += redS[r_][threadIdx.x];             \
      atomAddD(&(ST)[((CH_OFF) + threadIdx.x)*2], (double)s_);                 \
    } else if (threadIdx.x < 128){                                             \
      int o_ = threadIdx.x - 64;                                               \
      float s_ = 0.f;                                                          \
      _Pragma("unroll")                                                        \
      for (int r_ = 0; r_ < 16; ++r_) s_ += redQ[r_][o_];                      \
      atomAddD(&(ST)[((CH_OFF) + o_)*2 + 1], (double)s_);                      \
    }                                                                          \
  }

// ---------------- MLP layer 0: gather + 64->64 + bias -> y [64][P] ---------
__global__ __launch_bounds__(256, 2) void m0_kernel(const float* __restrict__ pT,
                                                    const float* __restrict__ xyz,
                                                    const float* __restrict__ nxyz,
                                                    const int* __restrict__ knn_idx,
                                                    const float* __restrict__ w,
                                                    const float* __restrict__ bias,
                                                    float* __restrict__ y,
                                                    double* __restrict__ stout){
  __shared__ float Wt[4096]; __shared__ float bb[64];
  __shared__ float redS[16][65], redQ[16][65];
  for (int t = threadIdx.x; t < 4096; t += 256){ int o = t >> 6, c = t & 63; Wt[c*64+o] = w[o*64+c]; }
  if (threadIdx.x < 64) bb[threadIdx.x] = bias[threadIdx.x];
  __syncthreads();
  const int p = blockIdx.x*256 + threadIdx.x;
  const int b = p >> 15, s = (p & 32767) >> 5;
  const int n = knn_idx[p];
  float in[64];
  {
    const float* xb = xyz + (size_t)b*3*N_;
    const int q = (b << 10) + s;
    in[0] = xb[n]       - nxyz[(size_t)q*3];
    in[1] = xb[N_+n]    - nxyz[(size_t)q*3+1];
    in[2] = xb[2*N_+n]  - nxyz[(size_t)q*3+2];
    const float* pr = pT + ((size_t)b*N_ + n)*64;   // 256B-aligned padded row
#pragma unroll
    for (int d = 0; d < 60; d += 4){
      float4 v = *reinterpret_cast<const float4*>(&pr[d]);
      in[3+d] = v.x; in[4+d] = v.y; in[5+d] = v.z; in[6+d] = v.w;
    }
    in[63] = pr[60];
  }
  float acc[64];
#pragma unroll
  for (int o = 0; o < 64; ++o) acc[o] = bb[o];
#pragma unroll
  for (int c = 0; c < 64; ++c){
    float x = in[c];
#pragma unroll
    for (int o = 0; o < 64; o += 4){
      float4 w4 = *reinterpret_cast<const float4*>(&Wt[c*64+o]);
      acc[o]   += x*w4.x; acc[o+1] += x*w4.y; acc[o+2] += x*w4.z; acc[o+3] += x*w4.w;
    }
  }
#pragma unroll
  for (int o = 0; o < 64; ++o) y[(size_t)o*P_ + p] = acc[o];
  STATS64(acc[o], stout, 0)
}

// ---------------- MLP layer 1: bn(relu) then 64->64, in place --------------
__global__ __launch_bounds__(256, 2) void m1_kernel(float* __restrict__ y,
                                                    const float* __restrict__ w,
                                                    const float* __restrict__ bias,
                                                    const double* __restrict__ stin,
                                                    const float* __restrict__ g,
                                                    const float* __restrict__ be,
                                                    double* __restrict__ stout){
  __shared__ float Wt[4096]; __shared__ float bb[64], sc[64], sh[64];
  __shared__ float redS[16][65], redQ[16][65];
  for (int t = threadIdx.x; t < 4096; t += 256){ int o = t >> 6, c = t & 63; Wt[c*64+o] = w[o*64+c]; }
  if (threadIdx.x < 64){
    bn_coeff(stin, g, be, threadIdx.x, (double)P_, &sc[threadIdx.x], &sh[threadIdx.x]);
    bb[threadIdx.x] = bias[threadIdx.x];
  }
  __syncthreads();
  const int p = blockIdx.x*256 + threadIdx.x;
  float in[64];
#pragma unroll
  for (int c = 0; c < 64; ++c){
    float x = y[(size_t)c*P_ + p];
    in[c] = fmaxf(0.f, fmaf(x, sc[c], sh[c]));
  }
  float acc[64];
#pragma unroll
  for (int o = 0; o < 64; ++o) acc[o] = bb[o];
#pragma unroll
  for (int c = 0; c < 64; ++c){
    float x = in[c];
#pragma unroll
    for (int o = 0; o < 64; o += 4){
      float4 w4 = *reinterpret_cast<const float4*>(&Wt[c*64+o]);
      acc[o]   += x*w4.x; acc[o+1] += x*w4.y; acc[o+2] += x*w4.z; acc[o+3] += x*w4.w;
    }
  }
#pragma unroll
  for (int o = 0; o < 64; ++o) y[(size_t)o*P_ + p] = acc[o];
  STATS64(acc[o], stout, 0)
}

// ---------------- MLP layer 2: bn(relu) then 64->128 (half per blockIdx.y) -
__global__ __launch_bounds__(256, 2) void m2_kernel(const float* __restrict__ y1,
                                                    float* __restrict__ y2,
                                                    const float* __restrict__ w,
                                                    const float* __restrict__ bias,
                                                    const double* __restrict__ stin,
                                                    const float* __restrict__ g,
                                                    const float* __restrict__ be,
                                                    double* __restrict__ stout){
  __shared__ float Wt[4096]; __shared__ float bb[64], sc[64], sh[64];
  __shared__ float redS[16][65], redQ[16][65];
  const int half = blockIdx.y;
  for (int t = threadIdx.x; t < 4096; t += 256){
    int o = t >> 6, c = t & 63;
    Wt[c*64+o] = w[(size_t)(half*64+o)*64 + c];
  }
  if (threadIdx.x < 64){
    bn_coeff(stin, g, be, threadIdx.x, (double)P_, &sc[threadIdx.x], &sh[threadIdx.x]);
    bb[threadIdx.x] = bias[half*64 + threadIdx.x];
  }
  __syncthreads();
  const int p = blockIdx.x*256 + threadIdx.x;
  float in[64];
#pragma unroll
  for (int c = 0; c < 64; ++c){
    float x = y1[(size_t)c*P_ + p];
    in[c] = fmaxf(0.f, fmaf(x, sc[c], sh[c]));
  }
  float acc[64];
#pragma unroll
  for (int o = 0; o < 64; ++o) acc[o] = bb[o];
#pragma unroll
  for (int c = 0; c < 64; ++c){
    float x = in[c];
#pragma unroll
    for (int o = 0; o < 64; o += 4){
      float4 w4 = *reinterpret_cast<const float4*>(&Wt[c*64+o]);
      acc[o]   += x*w4.x; acc[o+1] += x*w4.y; acc[o+2] += x*w4.z; acc[o+3] += x*w4.w;
    }
  }
#pragma unroll
  for (int o = 0; o < 64; ++o) y2[(size_t)(half*64+o)*P_ + p] = acc[o];
  STATS64(acc[o], stout, half*64)
}

// ---------------- WeightNet layer 0: gather g_norm, 3->8 + stats -----------
__global__ __launch_bounds__(256) void w0_kernel(const float* __restrict__ xyz,
                                                 const float* __restrict__ nxyz,
                                                 const int* __restrict__ knn_idx,
                                                 const float* __restrict__ w,   // [8][3]
                                                 const float* __restrict__ bias,
                                                 float* __restrict__ wb,
                                                 double* __restrict__ stout){
  __shared__ float Wl[24], bb[8];
  __shared__ float redS[16][9], redQ[16][9];
  if (threadIdx.x < 24) Wl[threadIdx.x] = w[threadIdx.x];
  if (threadIdx.x < 8)  bb[threadIdx.x] = bias[threadIdx.x];
  __syncthreads();
  const int p = blockIdx.x*256 + threadIdx.x;
  const int b = p >> 15, s = (p & 32767) >> 5;
  const int n = knn_idx[p];
  const float* xb = xyz + (size_t)b*3*N_;
  const int q = (b << 10) + s;
  float gx = xb[n]      - nxyz[(size_t)q*3];
  float gy = xb[N_+n]   - nxyz[(size_t)q*3+1];
  float gz = xb[2*N_+n] - nxyz[(size_t)q*3+2];
  float a_[8];
#pragma unroll
  for (int o = 0; o < 8; ++o){
    a_[o] = bb[o] + gx*Wl[o*3] + gy*Wl[o*3+1] + gz*Wl[o*3+2];
    wb[(size_t)o*P_ + p] = a_[o];
  }
#pragma unroll
  for (int o = 0; o < 8; ++o){
    float s1 = dpp_row_sum16(a_[o]);
    float q1 = dpp_row_sum16(a_[o]*a_[o]);
    if ((threadIdx.x & 15) == 15){ int rid = threadIdx.x >> 4; redS[rid][o] = s1; redQ[rid][o] = q1; }
  }
  __syncthreads();
  if (threadIdx.x < 8){
    float s_ = 0.f;
#pragma unroll
    for (int r = 0; r < 16; ++r) s_ += redS[r][threadIdx.x];
    atomAddD(&stout[threadIdx.x*2], (double)s_);
  } else if (threadIdx.x < 16){
    int o = threadIdx.x - 8;
    float s_ = 0.f;
#pragma unroll
    for (int r = 0; r < 16; ++r) s_ += redQ[r][o];
    atomAddD(&stout[o*2+1], (double)s_);
  }
}

// ---------------- WeightNet layer 1: bn relu 8->8 in place + stats ---------
__global__ __launch_bounds__(256) void w1_kernel(float* __restrict__ wb,
                                                 const float* __restrict__ w,   // [8][8]
                                                 const float* __restrict__ bias,
                                                 const double* __restrict__ stin,
                                                 const float* __restrict__ g,
                                                 const float* __restrict__ be,
                                                 double* __restrict__ stout){
  __shared__ float Wl[64], bb[8], sc[8], sh[8];
  __shared__ float redS[16][9], redQ[16][9];
  if (threadIdx.x < 64) Wl[threadIdx.x] = w[threadIdx.x];
  if (threadIdx.x < 8){
    bn_coeff(stin, g, be, threadIdx.x, (double)P_, &sc[threadIdx.x], &sh[threadIdx.x]);
    bb[threadIdx.x] = bias[threadIdx.x];
  }
  __syncthreads();
  const int p = blockIdx.x*256 + threadIdx.x;
  float in[8];
#pragma unroll
  for (int c = 0; c < 8; ++c){
    float x = wb[(size_t)c*P_ + p];
    in[c] = fmaxf(0.f, fmaf(x, sc[c], sh[c]));
  }
  float acc[8];
#pragma unroll
  for (int o = 0; o < 8; ++o){
    float a = bb[o];
#pragma unroll
    for (int c = 0; c < 8; ++c) a += in[c]*Wl[o*8+c];
    acc[o] = a;
  }
#pragma unroll
  for (int o = 0; o < 8; ++o) wb[(size_t)o*P_ + p] = acc[o];
#pragma unroll
  for (int o = 0; o < 8; ++o){
    float s1 = dpp_row_sum16(acc[o]);
    float q1 = dpp_row_sum16(acc[o]*acc[o]);
    if ((threadIdx.x & 15) == 15){ int rid = threadIdx.x >> 4; redS[rid][o] = s1; redQ[rid][o] = q1; }
  }
  __syncthreads();
  if (threadIdx.x < 8){
    float s_ = 0.f;
#pragma unroll
    for (int r = 0; r < 16; ++r) s_ += redS[r][threadIdx.x];
    atomAddD(&stout[threadIdx.x*2], (double)s_);
  } else if (threadIdx.x < 16){
    int o = threadIdx.x - 8;
    float s_ = 0.f;
#pragma unroll
    for (int r = 0; r < 16; ++r) s_ += redQ[r][o];
    atomAddD(&stout[o*2+1], (double)s_);
  }
}

// ---------------- WeightNet layer 2: bn relu 8->16 + stats -----------------
__global__ __launch_bounds__(256) void w2_kernel(const float* __restrict__ wb,
                                                 float* __restrict__ wb2,
                                                 const float* __restrict__ w,   // [16][8]
                                                 const float* __restrict__ bias,
                                                 const double* __restrict__ stin,
                                                 const float* __restrict__ g,
                                                 const float* __restrict__ be,
                                                 double* __restrict__ stout){
  __shared__ float Wl[128], bb[16], sc[8], sh[8];
  __shared__ float redS[16][17], redQ[16][17];
  if (threadIdx.x < 128) Wl[threadIdx.x] = w[threadIdx.x];
  if (threadIdx.x < 8)
    bn_coeff(stin, g, be, threadIdx.x, (double)P_, &sc[threadIdx.x], &sh[threadIdx.x]);
  if (threadIdx.x < 16) bb[threadIdx.x] = bias[threadIdx.x];
  __syncthreads();
  const int p = blockIdx.x*256 + threadIdx.x;
  float in[8];
#pragma unroll
  for (int c = 0; c < 8; ++c){
    float x = wb[(size_t)c*P_ + p];
    in[c] = fmaxf(0.f, fmaf(x, sc[c], sh[c]));
  }
  float acc[16];
#pragma unroll
  for (int o = 0; o < 16; ++o){
    float a = bb[o];
#pragma unroll
    for (int c = 0; c < 8; ++c) a += in[c]*Wl[o*8+c];
    acc[o] = a;
    wb2[(size_t)o*P_ + p] = a;
  }
#pragma unroll
  for (int o = 0; o < 16; ++o){
    float s1 = dpp_row_sum16(acc[o]);
    float q1 = dpp_row_sum16(acc[o]*acc[o]);
    if ((threadIdx.x & 15) == 15){ int rid = threadIdx.x >> 4; redS[rid][o] = s1; redQ[rid][o] = q1; }
  }
  __syncthreads();
  if (threadIdx.x < 16){
    float s_ = 0.f;
#pragma unroll
    for (int r = 0; r < 16; ++r) s_ += redS[r][threadIdx.x];
    atomAddD(&stout[threadIdx.x*2], (double)s_);
  } else if (threadIdx.x < 32){
    int o = threadIdx.x - 16;
    float s_ = 0.f;
#pragma unroll
    for (int r = 0; r < 16; ++r) s_ += redQ[r][o];
    atomAddD(&stout[o*2+1], (double)s_);
  }
}

// ---------------- agg: per (b,s) [128,K]x[K,16] -> agg row [2048] ----------
__global__ __launch_bounds__(256) void agg_kernel(const float* __restrict__ y2,
                                                  const float* __restrict__ wb2,
                                                  const double* __restrict__ st2,
                                                  const float* __restrict__ g2,
                                                  const float* __restrict__ be2,
                                                  const double* __restrict__ stw,
                                                  const float* __restrict__ gw,
                                                  const float* __restrict__ bew,
                                                  float* __restrict__ agg){
  __shared__ float f[32*132];      // [k][c] padded
  __shared__ float wt[32*16];      // [k][w]
  __shared__ float sc2[128], sh2[128], scw[16], shw[16];
  const int t = threadIdx.x;
  if (t < 128) bn_coeff(st2, g2, be2, t, (double)P_, &sc2[t], &sh2[t]);
  if (t < 16)  bn_coeff(stw, gw, bew, t, (double)P_, &scw[t], &shw[t]);
  __syncthreads();
  const int bs = blockIdx.x;
  const size_t p0 = (size_t)bs * 32;
  for (int e = t; e < 4096; e += 256){
    int c = e >> 5, k = e & 31;
    float x = y2[(size_t)c*P_ + p0 + k];
    f[k*132 + c] = fmaxf(0.f, fmaf(x, sc2[c], sh2[c]));
  }
  for (int e = t; e < 512; e += 256){
    int w = e >> 5, k = e & 31;
    float x = wb2[(size_t)w*P_ + p0 + k];
    wt[k*16 + w] = fmaxf(0.f, fmaf(x, scw[w], shw[w]));
  }
  __syncthreads();
  const int c = t >> 1, wp = (t & 1) * 8;
  float a0=0,a1=0,a2=0,a3=0,a4=0,a5=0,a6=0,a7=0;
#pragma unroll
  for (int k = 0; k < 32; ++k){
    float fv = f[k*132 + c];
    float4 u = *reinterpret_cast<const float4*>(&wt[k*16 + wp]);
    float4 v = *reinterpret_cast<const float4*>(&wt[k*16 + wp + 4]);
    a0 += fv*u.x; a1 += fv*u.y; a2 += fv*u.z; a3 += fv*u.w;
    a4 += fv*v.x; a5 += fv*v.y; a6 += fv*v.z; a7 += fv*v.w;
  }
  float* dst = agg + (size_t)bs*2048 + c*16 + wp;
  *reinterpret_cast<float4*>(dst)     = make_float4(a0,a1,a2,a3);
  *reinterpret_cast<float4*>(dst + 4) = make_float4(a4,a5,a6,a7);
}

// ---------------- linear GEMM: [8192,2048] x [128,2048]^T + b --------------
__global__ __launch_bounds__(256) void lin_kernel(const float* __restrict__ agg,
                                                  const float* __restrict__ lw,
                                                  const float* __restrict__ lb,
                                                  float* __restrict__ outp){
  __shared__ float A[32*33];        // [r][kk] padded
  __shared__ float Wl[32*128];      // [kk][o]
  __shared__ float lbs[128];
  const int t = threadIdx.x;
  const int r0 = blockIdx.x * 32;
  if (t < 128) lbs[t] = lb[t];
  const int c_lane = t & 31, rg = t >> 5;
  float acc[4][4];
#pragma unroll
  for (int i = 0; i < 4; ++i)
#pragma unroll
    for (int j = 0; j < 4; ++j) acc[i][j] = 0.f;

  for (int kk0 = 0; kk0 < 2048; kk0 += 32){
    __syncthreads();
    {
      int r = t >> 3, kq = (t & 7) * 4;
      float4 v = *reinterpret_cast<const float4*>(&agg[(size_t)(r0 + r)*2048 + kk0 + kq]);
      A[r*33 + kq]   = v.x; A[r*33 + kq+1] = v.y; A[r*33 + kq+2] = v.z; A[r*33 + kq+3] = v.w;
    }
    {
#pragma unroll
      for (int u = 0; u < 4; ++u){
        int fid = t + 256*u;
        int o = fid >> 3, kq = (fid & 7) * 4;
        float4 v = *reinterpret_cast<const float4*>(&lw[(size_t)o*2048 + kk0 + kq]);
        Wl[(kq  )*128 + o] = v.x; Wl[(kq+1)*128 + o] = v.y;
        Wl[(kq+2)*128 + o] = v.z; Wl[(kq+3)*128 + o] = v.w;
      }
    }
    __syncthreads();
#pragma unroll 8
    for (int kk = 0; kk < 32; ++kk){
      float a0 = A[(rg*4+0)*33 + kk], a1 = A[(rg*4+1)*33 + kk],
            a2 = A[(rg*4+2)*33 + kk], a3 = A[(rg*4+3)*33 + kk];
#pragma unroll
      for (int j = 0; j < 4; ++j){
        float wv = Wl[kk*128 + c_lane + 32*j];
        acc[0][j] += a0*wv; acc[1][j] += a1*wv; acc[2][j] += a2*wv; acc[3][j] += a3*wv;
      }
    }
  }
  __syncthreads();
#pragma unroll
  for (int i = 0; i < 4; ++i)
#pragma unroll
    for (int j = 0; j < 4; ++j){
      int o = c_lane + 32*j;
      outp[(size_t)(r0 + rg*4 + i)*128 + o] = acc[i][j] + lbs[o];
    }
}

// ---------------- final BN stats over (b,s) --------------------------------
__global__ __launch_bounds__(128) void statsF_kernel(const float* __restrict__ outp,
                                                     double* __restrict__ st){
  const int c = threadIdx.x;
  const int r0 = blockIdx.x * 128;
  double s = 0.0, q = 0.0;
  for (int r = 0; r < 128; ++r){
    double v = outp[(size_t)(r0 + r)*128 + c];
    s += v; q += v*v;
  }
  atomAddD(&st[c*2], s); atomAddD(&st[c*2+1], q);
}

// ---------------- final BN+relu + transpose to [B,128,S] -------------------
// block = 64 s-rows x 128 channels, LDS transpose for coalesced both sides
__global__ __launch_bounds__(256) void final_kernel(const float* __restrict__ outp,
                                                    const double* __restrict__ st,
                                                    const float* __restrict__ g,
                                                    const float* __restrict__ be,
                                                    float* __restrict__ out){
  __shared__ float sc[128], sh[128];
  __shared__ float tile[64][129];
  const int t = threadIdx.x;
  if (t < 128) bn_coeff(st, g, be, t, (double)BS_, &sc[t], &sh[t]);
  const int bs0 = blockIdx.x * 64;                 // 128 blocks
  const int b = bs0 >> 10, s0 = bs0 & 1023;
#pragma unroll
  for (int e = t; e < 8192; e += 256){
    int r = e >> 7, c = e & 127;
    tile[r][c] = outp[(size_t)(bs0 + r)*128 + c];
  }
  __syncthreads();
#pragma unroll
  for (int e = t; e < 8192; e += 256){
    int o = e >> 6, si = e & 63;
    float x = tile[si][o];
    out[(size_t)b*131072 + (size_t)o*1024 + s0 + si] = fmaxf(0.f, fmaf(x, sc[o], sh[o]));
  }
}

// ---------------------------------------------------------------------------
extern "C" void kernel_launch(void* const* d_in, const int* in_sizes, int n_in,
                              void* d_out, int out_size, void* d_ws, size_t ws_size,
                              hipStream_t stream){
  (void)in_sizes; (void)n_in; (void)out_size; (void)ws_size;
  const float* xyz    = (const float*)d_in[0];
  const float* points = (const float*)d_in[1];
  const float* mw0 = (const float*)d_in[2],  *mb0 = (const float*)d_in[3],
             * mg0 = (const float*)d_in[4],  *me0 = (const float*)d_in[5];
  const float* mw1 = (const float*)d_in[6],  *mb1 = (const float*)d_in[7],
             * mg1 = (const float*)d_in[8],  *me1 = (const float*)d_in[9];
  const float* mw2 = (const float*)d_in[10], *mb2 = (const float*)d_in[11],
             * mg2 = (const float*)d_in[12], *me2 = (const float*)d_in[13];
  const float* ww0 = (const float*)d_in[14], *wb0 = (const float*)d_in[15],
             * wg0 = (const float*)d_in[16], *we0 = (const float*)d_in[17];
  const float* ww1 = (const float*)d_in[18], *wb1 = (const float*)d_in[19],
             * wg1 = (const float*)d_in[20], *we1 = (const float*)d_in[21];
  const float* ww2 = (const float*)d_in[22], *wb2_ = (const float*)d_in[23],
             * wg2 = (const float*)d_in[24], *we2 = (const float*)d_in[25];
  const float* lw  = (const float*)d_in[26], *lb  = (const float*)d_in[27];
  const float* fg  = (const float*)d_in[28], *fb  = (const float*)d_in[29];

  char* ws = (char*)d_ws;
  double* ST0 = (double*)(ws + OFF_STATS);
  double* ST1 = (double*)(ws + OFF_STATS + 1024);
  double* ST2 = (double*)(ws + OFF_STATS + 2048);
  double* SW0 = (double*)(ws + OFF_STATS + 4096);
  double* SW1 = (double*)(ws + OFF_STATS + 4224);
  double* SW2 = (double*)(ws + OFF_STATS + 4352);
  double* STF = (double*)(ws + OFF_STATS + 4608);
  float* nxyz   = (float*)(ws + OFF_NEWXYZ);
  int*   knnidx = (int*)(ws + OFF_KNN);
  float* pT     = (float*)(ws + OFF_PT);
  float* y01    = (float*)(ws + OFF_Y01);
  float* y2     = (float*)(ws + OFF_Y2);
  float* w01    = (float*)(ws + OFF_W01);
  float* w2b    = (float*)(ws + OFF_W2B);
  float* aggbuf = (float*)(ws + OFF_Y01);   // alias: y01 dead after m2
  float* outpre = (float*)(ws + OFF_OUTPRE);// alias: w01 dead after w2

  float* out_xyz  = (float*)d_out;                      // [B,3,S]
  float* out_feat = (float*)d_out + (size_t)B_*3*S_;    // [B,128,S]

  hipMemsetAsync(ws + OFF_STATS, 0, 8192, stream);

  StartIdx st = compute_starts();
  fps_tr_kernel<<<dim3(8 + B_*64), dim3(512), 0, stream>>>(xyz, points, st, nxyz, out_xyz, pT);

  knn_kernel<<<dim3(BS_/4), dim3(256), 0, stream>>>(xyz, nxyz, knnidx);

  m0_kernel<<<dim3(P_/256), dim3(256), 0, stream>>>(pT, xyz, nxyz, knnidx, mw0, mb0, y01, ST0);
  m1_kernel<<<dim3(P_/256), dim3(256), 0, stream>>>(y01, mw1, mb1, ST0, mg0, me0, ST1);
  m2_kernel<<<dim3(P_/256, 2), dim3(256), 0, stream>>>(y01, y2, mw2, mb2, ST1, mg1, me1, ST2);

  w0_kernel<<<dim3(P_/256), dim3(256), 0, stream>>>(xyz, nxyz, knnidx, ww0, wb0, w01, SW0);
  w1_kernel<<<dim3(P_/256), dim3(256), 0, stream>>>(w01, ww1, wb1, SW0, wg0, we0, SW1);
  w2_kernel<<<dim3(P_/256), dim3(256), 0, stream>>>(w01, w2b, ww2, wb2_, SW1, wg1, we1, SW2);

  agg_kernel<<<dim3(BS_), dim3(256), 0, stream>>>(y2, w2b, ST2, mg2, me2, SW2, wg2, we2, aggbuf);
  lin_kernel<<<dim3(BS_/32), dim3(256), 0, stream>>>(aggbuf, lw, lb, outpre);
  statsF_kernel<<<dim3(BS_/128), dim3(128), 0, stream>>>(outpre, STF);
  final_kernel<<<dim3(BS_/64), dim3(256), 0, stream>>>(outpre, STF, fg, fb, out_feat);
}